// Round 10
// baseline (290.150 us; speedup 1.0000x reference)
//
#include <hip/hip_runtime.h>
#include <stdint.h>

typedef unsigned short u16;
typedef uint32_t u32;
typedef __bf16 bf16x8 __attribute__((ext_vector_type(8)));
typedef u16    u16x8  __attribute__((ext_vector_type(8)));
typedef float  f32x4  __attribute__((ext_vector_type(4)));
typedef u32    u32x4v __attribute__((ext_vector_type(4)));

constexpr int Bc = 2, Sc = 2048, DIMc = 2048, NHc = 16, NKVc = 4, HDc = 128;
constexpr int Mc  = Bc * Sc;          // 4096 rows
constexpr int QKVN = 3072;            // merged Q(2048) + K(512) + V(512) projection cols
constexpr float SCALE = 0.08838834764831845f; // 1/sqrt(128)

__device__ __forceinline__ u16 f2bf(float f) {
    uint32_t u = __builtin_bit_cast(uint32_t, f);
    u += 0x7FFFu + ((u >> 16) & 1u);   // RNE
    return (u16)(u >> 16);
}
__device__ __forceinline__ u32 pk2bf(float a, float b) {
    return (u32)f2bf(a) | ((u32)f2bf(b) << 16);
}

// async global->LDS, 16B per lane. LDS dest must be wave-uniform base + lane*16.
__device__ __forceinline__ void async_cp16(const u16* gsrc, u16* ldst) {
    __builtin_amdgcn_global_load_lds(
        (__attribute__((address_space(1))) void*)(gsrc),
        (__attribute__((address_space(3))) void*)(ldst), 16, 0, 0);
}

// ---------------- fused: headw+x-cast | Wq/Wkv cast | rope cos/sin table ----------------
// R9: HWB section rebuilt as 1024 blocks x 4 INDEPENDENT waves (one row per wave),
// zero LDS / zero barriers. Each lane holds its 8 x-row float4s in registers: the xb
// cast writes from regs (same coalesced quad indices as R8), and the 16-head gate dot
// runs against register-resident x (R8 re-read the row from LDS 16x, once per head,
// plus staged it with 2 barriers per single-row block). Gate math is bit-identical to
// the R5/R8-verified form: same per-lane partial order, same shfl_xor reduce chain.
constexpr int HWB2 = Mc / 4;              // 1024 blocks, 4 rows each (1 per wave)
constexpr int CQ1 = DIMc * DIMc / 4;      // Wq quads
constexpr int CQ2 = 1024 * DIMc / 4;      // Wkv quads
constexpr int NWQ = (CQ1 + CQ2) / 256;    // 6144 weight-cast blocks (Wo in gemm_qkv)
constexpr int NTB = Sc * 64 / 256;        // 512 rope-table blocks
__global__ __launch_bounds__(256) void cvt_hw(const float* __restrict__ x,
                                              const float* __restrict__ Wq,
                                              const float* __restrict__ Wkv,
                                              const float* __restrict__ Wr,
                                              const float* __restrict__ br,
                                              u16* __restrict__ xb,
                                              u16* __restrict__ Wqkvb,
                                              float* __restrict__ hw,
                                              float2* __restrict__ csT) {
    int bid = blockIdx.x;
    if (bid < HWB2) {
        const int wid = threadIdx.x >> 6, lane = threadIdx.x & 63;
        const int row = bid * 4 + wid;             // one row per wave, no cross-wave dep
        const float4* xg = (const float4*)(x + (size_t)row * 2048);
        float4 xv[8];
#pragma unroll
        for (int j = 0; j < 8; j++) xv[j] = xg[lane + j * 64];
        // xb cast from registers (coalesced: quad index lane + j*64)
        ushort4* dst = (ushort4*)(xb + (size_t)row * 2048);
#pragma unroll
        for (int j = 0; j < 8; j++) {
            float4 v = xv[j];
            ushort4 o;
            o.x = f2bf(v.x); o.y = f2bf(v.y); o.z = f2bf(v.z); o.w = f2bf(v.w);
            dst[lane + j * 64] = o;
        }
        // gate: 16 heads against register-resident x
#pragma unroll 1
        for (int h = 0; h < NHc; h++) {
            const float4* wr4 = (const float4*)(Wr + (size_t)h * 2048);
            float s = 0.f;
#pragma unroll
            for (int j = 0; j < 8; j++) {
                float4 wv = wr4[lane + j * 64];
                s += xv[j].x * wv.x + xv[j].y * wv.y + xv[j].z * wv.z + xv[j].w * wv.w;
            }
#pragma unroll
            for (int off = 32; off; off >>= 1) s += __shfl_xor(s, off, 64);
            if (lane == 0) hw[(size_t)row * NHc + h] = 1.f / (1.f + __expf(-(s + br[h])));
        }
        return;
    }
    bid -= HWB2;
    if (bid < NWQ) {
        int q = bid * 256 + threadIdx.x;
        const float* src; u16* dst; int qi;
        if (q < CQ1) { src = Wq;  dst = Wqkvb; qi = q; }
        else         { src = Wkv; dst = Wqkvb + (size_t)DIMc * DIMc; qi = q - CQ1; }
        float4 v = ((const float4*)src)[qi];
        ushort4 o;
        o.x = f2bf(v.x); o.y = f2bf(v.y); o.z = f2bf(v.z); o.w = f2bf(v.w);
        ((ushort4*)dst)[qi] = o;
        return;
    }
    bid -= NWQ;
    // rope table: csT[s*64+d] = {cos, sin}(s * 10000^(-d/64)) — matches reference math
    int idx = bid * 256 + threadIdx.x;
    int s = idx >> 6, d = idx & 63;
    float invf = powf(10000.0f, -(float)d * (1.0f / 64.0f));
    float ang = (float)s * invf;
    float2 cs;
    cs.x = cosf(ang);
    cs.y = sinf(ang);
    csT[idx] = cs;
}

// ---------------- QKV GEMM: 256x256 tile, 8-phase counted-vmcnt schedule (R4/R5) ----
// 1D grid 256 blocks = full chip: blocks 0..191 = GEMM tiles (n = bid%12, m = bid/12);
// blocks 192..255 cast Wo->bf16 in the GEMM's shadow (Wob consumed only by gemm_bt3,
// two launches later, same stream). K-loop byte-identical to the R4/R5-verified 8-phase
// counted-vmcnt schedule; epilogue fully unrolled (rule #20).
__global__ __launch_bounds__(512, 2) void gemm_qkv(const u16* __restrict__ A,
                                                   const u16* __restrict__ Bw,
                                                   const float* __restrict__ hw,
                                                   const float2* __restrict__ csT,
                                                   const float* __restrict__ Wo,
                                                   u16* __restrict__ Wob,
                                                   u16* __restrict__ Qr,
                                                   u16* __restrict__ Kb,
                                                   u16* __restrict__ Vt,
                                                   u16* __restrict__ Vg) {
    const int bidL = blockIdx.x;
    if (bidL >= 192) {
        // Wo cast: 64 blocks x 512 threads x 32 float4 = 1M quads
        const float4* src = (const float4*)Wo;
        ushort4* dst = (ushort4*)Wob;
        int i0 = (bidL - 192) * 16384 + threadIdx.x;
#pragma unroll
        for (int k = 0; k < 32; k++) {
            float4 v = src[i0 + k * 512];
            ushort4 o;
            o.x = f2bf(v.x); o.y = f2bf(v.y); o.z = f2bf(v.z); o.w = f2bf(v.w);
            dst[i0 + k * 512] = o;
        }
        return;
    }
    __shared__ __align__(16) u16 SM[4][2][128 * 64];   // 131072 B
    float* EpS = (float*)SM;                           // 64*261*4 = 66816 B, aliased
    const int Kd = DIMc;
    constexpr int NT = 32;                             // K-tiles
    const int tid  = threadIdx.x;
    const int lane = tid & 63;
    const int wid  = tid >> 6;
    const int m0 = (bidL / 12) * 256;
    const int n0 = (bidL % 12) * 256;
    const int wr = wid >> 2;            // 0..1 (M)
    const int wc = wid & 3;             // 0..3 (N)
    const int fr = lane & 15;
    const int fq = lane >> 4;
    const int f7 = fr & 7;

    // staging addresses: per half-tile, thread does 2 loads (slots tid, tid+512)
    const int s0 = tid, s1 = tid + 512;
    const int r0 = s0 >> 3, r1 = s1 >> 3;             // 0..127 row within half
    const int j0 = (s0 & 7) ^ (r0 & 7), j1 = (s1 & 7) ^ (r1 & 7);  // pre-swizzled src chunk
    const u16* gA0 = A  + (size_t)(m0 + r0) * Kd + j0 * 8;
    const u16* gA1 = A  + (size_t)(m0 + r1) * Kd + j1 * 8;
    const u16* gB0 = Bw + (size_t)(n0 + r0) * Kd + j0 * 8;
    const u16* gB1 = Bw + (size_t)(n0 + r1) * Kd + j1 * 8;
    const size_t hK = (size_t)128 * Kd;

    auto stA = [&](int buf, int h, int t) {
        async_cp16(gA0 + h * hK + t * 64, &SM[buf][h][s0 * 8]);
        async_cp16(gA1 + h * hK + t * 64, &SM[buf][h][s1 * 8]);
    };
    auto stB = [&](int buf, int h, int t) {
        async_cp16(gB0 + h * hK + t * 64, &SM[2 + buf][h][s0 * 8]);
        async_cp16(gB1 + h * hK + t * 64, &SM[2 + buf][h][s1 * 8]);
    };

    f32x4 acc[8][4];
#pragma unroll
    for (int i = 0; i < 8; i++)
#pragma unroll
        for (int j = 0; j < 4; j++) {
            f32x4 z = {0.f, 0.f, 0.f, 0.f};
            acc[i][j] = z;
        }

    const int c0 = ((fq) ^ f7) * 8;       // ks=0 chunk offset (u16 units)
    const int c1 = ((4 + fq) ^ f7) * 8;   // ks=1 chunk
    bf16x8 afl[4][2], afh[4][2], bfl[2][2], bfh[2][2];

    auto rdA = [&](bf16x8 (&af)[4][2], int tb, int mh) {
        const u16* Ab = SM[tb][wr];       // wave wr reads only A-half wr
#pragma unroll
        for (int m2 = 0; m2 < 4; m2++) {
            int row = (mh * 4 + m2) * 16 + fr;
            af[m2][0] = __builtin_bit_cast(bf16x8, *(const u16x8*)(Ab + row * 64 + c0));
            af[m2][1] = __builtin_bit_cast(bf16x8, *(const u16x8*)(Ab + row * 64 + c1));
        }
    };
    auto rdB = [&](bf16x8 (&bf)[2][2], int tb, int nh) {
        const u16* Bb = SM[2 + tb][wc >> 1];   // wave wc reads only B-half wc>>1
#pragma unroll
        for (int n2 = 0; n2 < 2; n2++) {
            int row = (wc & 1) * 64 + (nh * 2 + n2) * 16 + fr;
            bf[n2][0] = __builtin_bit_cast(bf16x8, *(const u16x8*)(Bb + row * 64 + c0));
            bf[n2][1] = __builtin_bit_cast(bf16x8, *(const u16x8*)(Bb + row * 64 + c1));
        }
    };
    auto mma = [&](bf16x8 (&af)[4][2], bf16x8 (&bf)[2][2], int mh, int nh) {
        __builtin_amdgcn_s_setprio(1);
#pragma unroll
        for (int m2 = 0; m2 < 4; m2++)
#pragma unroll
            for (int n2 = 0; n2 < 2; n2++) {
                acc[mh * 4 + m2][nh * 2 + n2] =
                    __builtin_amdgcn_mfma_f32_16x16x32_bf16(af[m2][0], bf[n2][0],
                                                            acc[mh * 4 + m2][nh * 2 + n2], 0, 0, 0);
                acc[mh * 4 + m2][nh * 2 + n2] =
                    __builtin_amdgcn_mfma_f32_16x16x32_bf16(af[m2][1], bf[n2][1],
                                                            acc[mh * 4 + m2][nh * 2 + n2], 0, 0, 0);
            }
        __builtin_amdgcn_s_setprio(0);
    };

#define LGK0 do { asm volatile("s_waitcnt lgkmcnt(0)" ::: "memory"); \
                  __builtin_amdgcn_sched_barrier(0); } while (0)
#define BAR  __builtin_amdgcn_s_barrier()

    // prologue: tile0 (A,B) + tile1 B halves = 12 loads; drain to tile0 complete
    stA(0, 0, 0); stA(0, 1, 0); stB(0, 0, 0); stB(0, 1, 0);
    stB(1, 0, 1); stB(1, 1, 1);
    asm volatile("s_waitcnt vmcnt(4)" ::: "memory");
    BAR;

#pragma unroll 1
    for (int i = 0; i < NT / 2; i++) {
        const int t0 = 2 * i, t1 = 2 * i + 1;
        // ---- ph1: tile t0 quadrant (0,0) ----
        rdA(afl, 0, 0); rdB(bfl, 0, 0);
        stA(1, 0, t1);
        BAR; LGK0; mma(afl, bfl, 0, 0); BAR;
        // ---- ph2: (0,1) ----
        rdB(bfh, 0, 1);
        stA(1, 1, t1);
        BAR; LGK0; mma(afl, bfh, 0, 1); BAR;
        // ---- ph3: (1,0) ----
        rdA(afh, 0, 1);
        if (t0 + 2 < NT) stB(0, 0, t0 + 2);
        BAR; LGK0; mma(afh, bfl, 1, 0); BAR;
        // ---- ph4: (1,1); counted vmcnt ----
        if (t0 + 2 < NT) {
            stB(0, 1, t0 + 2);
            asm volatile("s_waitcnt vmcnt(4)" ::: "memory");   // t1 fully landed; 2 halves fly
        } else {
            asm volatile("s_waitcnt vmcnt(0)" ::: "memory");   // tail
        }
        BAR; __builtin_amdgcn_sched_barrier(0); mma(afh, bfh, 1, 1); BAR;
        // ---- ph5: tile t1 quadrant (0,0) ----
        rdA(afl, 1, 0); rdB(bfl, 1, 0);
        if (t0 + 2 < NT) stA(0, 0, t0 + 2);
        BAR; LGK0; mma(afl, bfl, 0, 0); BAR;
        // ---- ph6: (0,1) ----
        rdB(bfh, 1, 1);
        if (t0 + 2 < NT) stA(0, 1, t0 + 2);
        BAR; LGK0; mma(afl, bfh, 0, 1); BAR;
        // ---- ph7: (1,0) ----
        rdA(afh, 1, 1);
        if (t1 + 2 < NT) stB(1, 0, t1 + 2);
        BAR; LGK0; mma(afh, bfl, 1, 0); BAR;
        // ---- ph8: (1,1); counted vmcnt ----
        if (t1 + 2 < NT) {
            stB(1, 1, t1 + 2);
            asm volatile("s_waitcnt vmcnt(4)" ::: "memory");   // t0+2 fully landed
        } else {
            asm volatile("s_waitcnt vmcnt(0)" ::: "memory");   // tail: drains everything
        }
        BAR; __builtin_amdgcn_sched_barrier(0); mma(afh, bfh, 1, 1); BAR;
    }
#undef LGK0
#undef BAR

    // ---- fused epilogue: 4 passes of 64 rows x 256 cols (2 heads). FULLY UNROLLED so
    // acc indices are static (rule #20) — p, m2, nj, r all compile-time constants. ----
    const int tL = n0 >> 7;                // even; heads tL, tL+1 (same kind)
    const int bb = m0 >> 11;               // batch (256-row tile never crosses)
    const int sb_t = m0 & 2047;
#pragma unroll
    for (int p = 0; p < 4; p++) {
        __syncthreads();                   // prior pass / K-loop reads done
        if (wr == (p >> 1)) {
#pragma unroll
            for (int m2 = 0; m2 < 4; m2++) {
#pragma unroll
                for (int nj = 0; nj < 4; nj++) {
                    int lr = m2 * 16 + fq * 4;
                    int col = wc * 64 + nj * 16 + fr;
#pragma unroll
                    for (int r = 0; r < 4; r++)
                        EpS[(lr + r) * 261 + col] = acc[(p & 1) * 4 + m2][nj][r];
                }
            }
        }
        __syncthreads();
        const int sbase = sb_t + p * 64;
        if (tL < 20) {
            // rope path (Q: gate+scale; K: plain), both heads of this tile
            const int d = tid & 63, rg = tid >> 6;
#pragma unroll 1
            for (int ch = 0; ch < 2; ch++) {
                const int t = tL + ch;
#pragma unroll
                for (int tt = 0; tt < 8; tt++) {
                    int lr = rg + 8 * tt;
                    int s = sbase + lr;
                    float v1 = EpS[lr * 261 + ch * 128 + d];
                    float v2 = EpS[lr * 261 + ch * 128 + 64 + d];
                    float2 cs = csT[(s << 6) + d];
                    float o1 = v1 * cs.x - v2 * cs.y;
                    float o2 = v2 * cs.x + v1 * cs.y;
                    if (t < 16) {
                        float w = hw[(size_t)((bb << 11) + s) * NHc + t] * SCALE;
                        size_t g = ((size_t)(bb * NHc + t) << 11) + s;
                        Qr[g * HDc + d]      = f2bf(o1 * w);
                        Qr[g * HDc + 64 + d] = f2bf(o2 * w);
                    } else {
                        size_t g = ((size_t)(bb * NKVc + (t - 16)) << 11) + s;
                        Kb[g * HDc + d]      = f2bf(o1);
                        Kb[g * HDc + 64 + d] = f2bf(o2);
                    }
                }
            }
        } else {
            // V transpose path + strided global-V gather, both heads
            const int sl = tid & 63, dg = tid >> 6;
            const int sg = sbase + sl;
#pragma unroll 1
            for (int ch = 0; ch < 2; ch++) {
                const int bhv = bb * NKVc + (tL + ch - 20);
                u16* Vbase = Vt + (size_t)bhv * HDc * Sc;
#pragma unroll
                for (int tt = 0; tt < 16; tt++) {
                    int d = dg + 8 * tt;
                    u16 bv = f2bf(EpS[sl * 261 + ch * 128 + d]);
                    Vbase[(size_t)d * Sc + sg] = bv;
                    if ((sg & 63) == 0)
                        Vg[(size_t)bhv * 4096 + d * 32 + (sg >> 6)] = bv;
                }
            }
        }
    }
}

// ---------------- bf16 GEMM (O-proj), 256x128 tile, 4-phase counted-vmcnt pipeline ----
// C[M,N] = A[M,K] * W[N,K]^T (fp32 out). 512 threads = 8 waves (4M x 2N), wave tile 64x64,
// BK=64. Grid (16,16) = 256 blocks = exactly 1 block/CU.
__global__ __launch_bounds__(512, 2) void gemm_bt3(const u16* __restrict__ A,
                                                   const u16* __restrict__ Bw,
                                                   float* __restrict__ C,
                                                   int Mdim, int Ndim, int Kdim) {
    __shared__ __align__(16) u16 As[2][256 * 64];   // 64 KB
    __shared__ __align__(16) u16 Bs[2][128 * 64];   // 32 KB
    const int tid  = threadIdx.x;
    const int lane = tid & 63;
    const int wid  = tid >> 6;
    const int m0 = blockIdx.y * 256;
    const int n0 = blockIdx.x * 128;
    const int wm = (wid >> 1) * 64;     // 4 M-waves
    const int wn = (wid & 1) * 64;      // 2 N-waves
    const int fr = lane & 15;
    const int fq = lane >> 4;
    const int f7 = fr & 7;

    // staging: pre-swizzled global source, linear LDS dest (16B/lane)
    const u16* gA[4]; const u16* gB[2];
    int sOffA[4], sOffB[2];
#pragma unroll
    for (int q = 0; q < 4; q++) {
        int s = tid + q * 512;          // 0..2047 16B-slots, 256 rows x 8 slots
        int row = s >> 3;
        int j = (s & 7) ^ (row & 7);    // XOR swizzle within row
        gA[q] = A + (size_t)(m0 + row) * Kdim + j * 8;
        sOffA[q] = s * 8;
    }
#pragma unroll
    for (int q = 0; q < 2; q++) {
        int s = tid + q * 512;          // 0..1023 16B-slots, 128 rows x 8 slots
        int row = s >> 3;
        int j = (s & 7) ^ (row & 7);
        gB[q] = Bw + (size_t)(n0 + row) * Kdim + j * 8;
        sOffB[q] = s * 8;
    }

    f32x4 acc[4][4];
#pragma unroll
    for (int i = 0; i < 4; i++)
#pragma unroll
        for (int j = 0; j < 4; j++) {
            f32x4 z = {0.f, 0.f, 0.f, 0.f};
            acc[i][j] = z;
        }

    const int NT = Kdim >> 6;
    const int c0 = ((fq) ^ f7) * 8;       // kh0 chunk offset (u16 units)
    const int c1 = ((4 + fq) ^ f7) * 8;   // kh1 chunk

    // prologue: stage tile 0 then tile 1 (issue order matters for vmcnt counting)
#pragma unroll
    for (int q = 0; q < 4; q++) async_cp16(gA[q], &As[0][sOffA[q]]);
#pragma unroll
    for (int q = 0; q < 2; q++) async_cp16(gB[q], &Bs[0][sOffB[q]]);
#pragma unroll
    for (int q = 0; q < 4; q++) async_cp16(gA[q] + 64, &As[1][sOffA[q]]);
#pragma unroll
    for (int q = 0; q < 2; q++) async_cp16(gB[q] + 64, &Bs[1][sOffB[q]]);

    for (int t = 0; t < NT; t++) {
        const u16* At = As[t & 1];
        const u16* Bt = Bs[t & 1];

        // ---- P0 ----
        if (t + 1 < NT) {
            asm volatile("s_waitcnt vmcnt(6)" ::: "memory");   // tile t landed; t+1 in flight
        } else {
            asm volatile("s_waitcnt vmcnt(0)" ::: "memory");   // tail: nothing newer queued
        }
        __builtin_amdgcn_s_barrier();

        bf16x8 af0[4], bf0[4];
#pragma unroll
        for (int i = 0; i < 4; i++)
            af0[i] = __builtin_bit_cast(bf16x8, *(const u16x8*)(At + (wm + i * 16 + fr) * 64 + c0));
#pragma unroll
        for (int j = 0; j < 4; j++)
            bf0[j] = __builtin_bit_cast(bf16x8, *(const u16x8*)(Bt + (wn + j * 16 + fr) * 64 + c0));
        asm volatile("s_waitcnt lgkmcnt(0)" ::: "memory");
        __builtin_amdgcn_sched_barrier(0);
        __builtin_amdgcn_s_setprio(1);
#pragma unroll
        for (int i = 0; i < 2; i++)
#pragma unroll
            for (int j = 0; j < 4; j++)
                acc[i][j] = __builtin_amdgcn_mfma_f32_16x16x32_bf16(af0[i], bf0[j], acc[i][j], 0, 0, 0);
        __builtin_amdgcn_s_setprio(0);

        // ---- P1 ---- (read kh1 frags; compute kh0 second half; then release buffer)
        bf16x8 af1[4], bf1[4];
#pragma unroll
        for (int i = 0; i < 4; i++)
            af1[i] = __builtin_bit_cast(bf16x8, *(const u16x8*)(At + (wm + i * 16 + fr) * 64 + c1));
#pragma unroll
        for (int j = 0; j < 4; j++)
            bf1[j] = __builtin_bit_cast(bf16x8, *(const u16x8*)(Bt + (wn + j * 16 + fr) * 64 + c1));
        __builtin_amdgcn_s_setprio(1);
#pragma unroll
        for (int i = 2; i < 4; i++)
#pragma unroll
            for (int j = 0; j < 4; j++)
                acc[i][j] = __builtin_amdgcn_mfma_f32_16x16x32_bf16(af0[i], bf0[j], acc[i][j], 0, 0, 0);
        __builtin_amdgcn_s_setprio(0);
        asm volatile("s_waitcnt lgkmcnt(0)" ::: "memory");     // all tile-t LDS reads complete
        __builtin_amdgcn_sched_barrier(0);
        __builtin_amdgcn_s_barrier();                          // buffer t&1 now free block-wide

        // ---- P2 ---- (stage A of tile t+2 into freed buffer; compute kh1 first half)
        if (t + 2 < NT) {
#pragma unroll
            for (int q = 0; q < 4; q++)
                async_cp16(gA[q] + (size_t)(t + 2) * 64, &As[t & 1][sOffA[q]]);
        }
        __builtin_amdgcn_s_setprio(1);
#pragma unroll
        for (int i = 0; i < 2; i++)
#pragma unroll
            for (int j = 0; j < 4; j++)
                acc[i][j] = __builtin_amdgcn_mfma_f32_16x16x32_bf16(af1[i], bf1[j], acc[i][j], 0, 0, 0);
        __builtin_amdgcn_s_setprio(0);

        // ---- P3 ---- (stage B of tile t+2; compute kh1 second half)
        if (t + 2 < NT) {
#pragma unroll
            for (int q = 0; q < 2; q++)
                async_cp16(gB[q] + (size_t)(t + 2) * 64, &Bs[t & 1][sOffB[q]]);
        }
        __builtin_amdgcn_s_setprio(1);
#pragma unroll
        for (int i = 2; i < 4; i++)
#pragma unroll
            for (int j = 0; j < 4; j++)
                acc[i][j] = __builtin_amdgcn_mfma_f32_16x16x32_bf16(af1[i], bf1[j], acc[i][j], 0, 0, 0);
        __builtin_amdgcn_s_setprio(0);
    }

    // ---- epilogue: fp32 C write (same C/D mapping as verified 128^2 kernel) ----
#pragma unroll
    for (int i = 0; i < 4; i++)
#pragma unroll
        for (int j = 0; j < 4; j++) {
            int row = m0 + wm + i * 16 + fq * 4;
            int col = n0 + wn + j * 16 + fr;
#pragma unroll
            for (int r = 0; r < 4; r++)
                C[(size_t)(row + r) * Ndim + col] = acc[i][j][r];
        }
}

// ---------------- MFMA flash attention helpers ----------------
__device__ __forceinline__ float colreduce_max(f32x4 a, f32x4 b) {
    float m = fmaxf(fmaxf(fmaxf(a[0], a[1]), fmaxf(a[2], a[3])),
                    fmaxf(fmaxf(b[0], b[1]), fmaxf(b[2], b[3])));
    m = fmaxf(m, __shfl_xor(m, 16, 64));
    m = fmaxf(m, __shfl_xor(m, 32, 64));
    return m;
}

// exp(S^T) C-frags -> B-operand frag (K=32) for mfma_f32_16x16x32_bf16, via shuffles
__device__ __forceinline__ bf16x8 build_pfrag(u32 pk0, u32 pk1, u32 pk2, u32 pk3, int lane) {
    const int c = lane & 15, Q = lane >> 4;
    const int sl0 = ((Q & 1) * 2) * 16 + c;
    const int sl1 = sl0 + 16;
    u32 a0 = (u32)__shfl((int)pk0, sl0, 64), b0 = (u32)__shfl((int)pk2, sl0, 64);
    u32 a1 = (u32)__shfl((int)pk1, sl0, 64), b1 = (u32)__shfl((int)pk3, sl0, 64);
    u32 a2 = (u32)__shfl((int)pk0, sl1, 64), b2 = (u32)__shfl((int)pk2, sl1, 64);
    u32 a3 = (u32)__shfl((int)pk1, sl1, 64), b3 = (u32)__shfl((int)pk3, sl1, 64);
    const bool hi = Q >= 2;
    u32x4v r = { hi ? b0 : a0, hi ? b1 : a1, hi ? b2 : a2, hi ? b3 : a3 };
    return __builtin_bit_cast(bf16x8, r);
}

// ---------------- attn3: 256-thread blocks, 64 queries, LDS-staged K/V double buffer ----
__global__ __launch_bounds__(256) void attn3(const u16* __restrict__ Qr,
                                             const u16* __restrict__ Kb,
                                             const u16* __restrict__ Vt,
                                             const u16* __restrict__ Vg,
                                             u16* __restrict__ attnb) {
    __shared__ __align__(16) u16 Ksh[2 * 4096];
    __shared__ __align__(16) u16 Vsh[2 * 4096];
    const int tid  = threadIdx.x;
    const int lane = tid & 63, wid = tid >> 6;
    const int bid  = blockIdx.x;                   // 0..1023
    const int q64  = (31 - (bid >> 5)) << 6;       // heavy blocks dispatched first
    const int bh   = bid & 31;
    const int h    = bh & 15;
    const int b    = bh >> 4;
    const int qw   = q64 + wid * 16;
    const int c = lane & 15, Q = lane >> 4;
    const int kvh = h >> 2;

    const u16* Qp = Qr + ((size_t)((b * NHc + h) * Sc + qw)) * HDc;
    const u16* Kh = Kb + (size_t)(b * NKVc + kvh) * Sc * HDc;
    const u16* Vh = Vt + (size_t)(b * NKVc + kvh) * HDc * Sc;
    const u16* Vgh = Vg + (size_t)(b * NKVc + kvh) * HDc * 32;

    const int kp0 = (q64 >= 256) ? (q64 - 256) : 0;
    const int nstages = (q64 + 64 - kp0) >> 5;     // <= 10

    auto stageLoad = [&](int bufi, int kp) {
        u16* Kd = Ksh + bufi * 4096;
        u16* Vd = Vsh + bufi * 4096;
#pragma unroll
        for (int qq = 0; qq < 2; qq++) {
            int s = tid + qq * 256;
            int kr = s >> 4;
            int jk = (s & 15) ^ (kr & 15);
            async_cp16(Kh + (size_t)(kp + kr) * HDc + jk * 8, Kd + s * 8);
            int dv = s >> 2;
            int jv = (s & 3) ^ ((dv >> 2) & 3);
            async_cp16(Vh + (size_t)dv * Sc + kp + jv * 8, Vd + s * 8);
        }
    };

    bf16x8 qf[4];
#pragma unroll
    for (int ch = 0; ch < 4; ch++)
        qf[ch] = __builtin_bit_cast(bf16x8, *(const u16x8*)(Qp + c * HDc + ch * 32 + Q * 8));

    stageLoad(0, kp0);   // prologue

    // ---- global branch: 32 strided keys, unmasked, exact softmax ----
    f32x4 sg0 = {0.f,0.f,0.f,0.f}, sg1 = {0.f,0.f,0.f,0.f};
#pragma unroll
    for (int ch = 0; ch < 4; ch++) {
        bf16x8 k0 = __builtin_bit_cast(bf16x8, *(const u16x8*)(Kh + ((size_t)c << 6) * HDc + ch * 32 + Q * 8));
        bf16x8 k1 = __builtin_bit_cast(bf16x8, *(const u16x8*)(Kh + ((size_t)(c + 16) << 6) * HDc + ch * 32 + Q * 8));
        sg0 = __builtin_amdgcn_mfma_f32_16x16x32_bf16(k0, qf[ch], sg0, 0, 0, 0);
        sg1 = __builtin_amdgcn_mfma_f32_16x16x32_bf16(k1, qf[ch], sg1, 0, 0, 0);
    }
    float mg = colreduce_max(sg0, sg1);
    f32x4 pg0, pg1;
    float gsum = 0.f;
#pragma unroll
    for (int r = 0; r < 4; r++) {
        pg0[r] = __expf(sg0[r] - mg);
        pg1[r] = __expf(sg1[r] - mg);
        gsum += pg0[r] + pg1[r];
    }
    gsum += __shfl_xor(gsum, 16, 64);
    gsum += __shfl_xor(gsum, 32, 64);
    const float lG = gsum;
    bf16x8 pgf = build_pfrag(pk2bf(pg0[0], pg0[1]), pk2bf(pg0[2], pg0[3]),
                             pk2bf(pg1[0], pg1[1]), pk2bf(pg1[2], pg1[3]), lane);
    f32x4 OG[8];
#pragma unroll
    for (int dt = 0; dt < 8; dt++) {
        bf16x8 vf = __builtin_bit_cast(bf16x8, *(const u16x8*)(Vgh + (dt * 16 + c) * 32 + Q * 8));
        f32x4 z = {0.f, 0.f, 0.f, 0.f};
        OG[dt] = __builtin_amdgcn_mfma_f32_16x16x32_bf16(vf, pgf, z, 0, 0, 0);
    }

    // ---- local branch: window [q-256, q], online softmax over LDS-staged stages ----
    f32x4 OL[8];
#pragma unroll
    for (int dt = 0; dt < 8; dt++) { f32x4 z = {0.f,0.f,0.f,0.f}; OL[dt] = z; }
    float mL = -1e30f, lL = 0.f;

    for (int ip = 0; ip < nstages; ip++) {
        const int kp = kp0 + ip * 32;
        __syncthreads();
        if (ip + 1 < nstages) stageLoad((ip + 1) & 1, kp + 32);
        const u16* Kd = Ksh + (ip & 1) * 4096;
        const u16* Vd = Vsh + (ip & 1) * 4096;

        if (kp > qw + 15 || kp + 31 < qw - 256) continue;   // wave-uniform skip

        f32x4 s0 = {0.f,0.f,0.f,0.f}, s1 = {0.f,0.f,0.f,0.f};
#pragma unroll
        for (int ch = 0; ch < 4; ch++) {
            int jj = ch * 4 + Q;
            bf16x8 k0 = __builtin_bit_cast(bf16x8, *(const u16x8*)(Kd + (c * 16 + (jj ^ c)) * 8));
            bf16x8 k1 = __builtin_bit_cast(bf16x8, *(const u16x8*)(Kd + ((16 + c) * 16 + (jj ^ c)) * 8));
            s0 = __builtin_amdgcn_mfma_f32_16x16x32_bf16(k0, qf[ch], s0, 0, 0, 0);
            s1 = __builtin_amdgcn_mfma_f32_16x16x32_bf16(k1, qf[ch], s1, 0, 0, 0);
        }
        if ((kp + 31 > qw) || (kp < qw - 241)) {
            const int q = qw + c;
#pragma unroll
            for (int r = 0; r < 4; r++) {
                int kk0 = kp + Q * 4 + r;
                int kk1 = kk0 + 16;
                if (kk0 > q || kk0 + 256 < q) s0[r] = -1e30f;
                if (kk1 > q || kk1 + 256 < q) s1[r] = -1e30f;
            }
        }
        float mx = colreduce_max(s0, s1);
        float mnew = fmaxf(mL, mx);
        float alpha = __expf(mL - mnew);
        f32x4 p0, p1;
        float sum = 0.f;
#pragma unroll
        for (int r = 0; r < 4; r++) {
            p0[r] = __expf(s0[r] - mnew);
            p1[r] = __expf(s1[r] - mnew);
            sum += p0[r] + p1[r];
        }
        sum += __shfl_xor(sum, 16, 64);
        sum += __shfl_xor(sum, 32, 64);
        lL = lL * alpha + sum;
        mL = mnew;
        bf16x8 pf = build_pfrag(pk2bf(p0[0], p0[1]), pk2bf(p0[2], p0[3]),
                                pk2bf(p1[0], p1[1]), pk2bf(p1[2], p1[3]), lane);
#pragma unroll
        for (int dt = 0; dt < 8; dt++) {
            int d = dt * 16 + c;
            bf16x8 vf = __builtin_bit_cast(bf16x8, *(const u16x8*)(Vd + (d * 4 + (Q ^ (c >> 2))) * 8));
            OL[dt] = OL[dt] * alpha;
            OL[dt] = __builtin_amdgcn_mfma_f32_16x16x32_bf16(vf, pf, OL[dt], 0, 0, 0);
        }
    }

    // ---- epilogue: 0.7*local + 0.3*global, write bf16 [B,S,DIM] ----
    const float rL = 0.7f / lL, rG = 0.3f / lG;
    u16* orow = attnb + ((size_t)(b * Sc + qw + c)) * DIMc + h * HDc;
#pragma unroll
    for (int dt = 0; dt < 8; dt++) {
        ushort4 ov;
        ov.x = f2bf(OL[dt][0] * rL + OG[dt][0] * rG);
        ov.y = f2bf(OL[dt][1] * rL + OG[dt][1] * rG);
        ov.z = f2bf(OL[dt][2] * rL + OG[dt][2] * rG);
        ov.w = f2bf(OL[dt][3] * rL + OG[dt][3] * rG);
        *(ushort4*)(orow + dt * 16 + Q * 4) = ov;
    }
}

extern "C" void kernel_launch(void* const* d_in, const int* in_sizes, int n_in,
                              void* d_out, int out_size, void* d_ws, size_t ws_size,
                              hipStream_t stream) {
    const float* x   = (const float*)d_in[0];
    const float* Wq  = (const float*)d_in[1];
    const float* Wkv = (const float*)d_in[2];
    const float* Wo  = (const float*)d_in[3];
    const float* Wr  = (const float*)d_in[4];
    const float* br  = (const float*)d_in[5];
    float* out = (float*)d_out;

    // workspace layout (~98 MB)
    char* p = (char*)d_ws;
    u16* xb    = (u16*)p;   p += (size_t)Mc * DIMc * 2;
    u16* Wqkvb = (u16*)p;   p += (size_t)QKVN * DIMc * 2;    // Wq rows then Wkv rows
    u16* Wob   = (u16*)p;   p += (size_t)DIMc * DIMc * 2;
    float* hw  = (float*)p; p += (size_t)Mc * NHc * 4;
    float2* csT = (float2*)p; p += (size_t)Sc * 64 * 8;      // rope cos/sin table, 1 MB
    u16* Qrb   = (u16*)p;   p += (size_t)Mc * DIMc * 2;
    u16* Kb16  = (u16*)p;   p += (size_t)Bc * NKVc * Sc * HDc * 2;
    u16* Vt16  = (u16*)p;   p += (size_t)Bc * NKVc * HDc * Sc * 2;
    u16* Vg16  = (u16*)p;   p += (size_t)Bc * NKVc * HDc * 32 * 2;
    u16* attnb = (u16*)p;   p += (size_t)Mc * DIMc * 2;

    cvt_hw<<<HWB2 + NWQ + NTB, 256, 0, stream>>>(x, Wq, Wkv, Wr, br, xb, Wqkvb, hw, csT);

    // 1D grid: 192 GEMM tiles + 64 Wo-cast blocks = 256 = full chip
    gemm_qkv<<<256, 512, 0, stream>>>(xb, Wqkvb, hw, csT, Wo, Wob, Qrb, Kb16, Vt16, Vg16);

    attn3<<<Bc * NHc * (Sc / 64), 256, 0, stream>>>(Qrb, Kb16, Vt16, Vg16, attnb);

    dim3 go(DIMc / 128, Mc / 256);     // (16, 16) = 256 blocks, 512 threads, 1 block/CU
    gemm_bt3<<<go, 512, 0, stream>>>(attnb, Wob, out, Mc, DIMc, DIMc);
}

// Round 11
// 283.820 us; speedup vs baseline: 1.0223x; 1.0223x over previous
//
#include <hip/hip_runtime.h>
#include <stdint.h>

typedef unsigned short u16;
typedef uint32_t u32;
typedef __bf16 bf16x8 __attribute__((ext_vector_type(8)));
typedef u16    u16x8  __attribute__((ext_vector_type(8)));
typedef float  f32x4  __attribute__((ext_vector_type(4)));
typedef u32    u32x4v __attribute__((ext_vector_type(4)));

constexpr int Bc = 2, Sc = 2048, DIMc = 2048, NHc = 16, NKVc = 4, HDc = 128;
constexpr int Mc  = Bc * Sc;          // 4096 rows
constexpr int QKVN = 3072;            // merged Q(2048) + K(512) + V(512) projection cols
constexpr float SCALE = 0.08838834764831845f; // 1/sqrt(128)

__device__ __forceinline__ u16 f2bf(float f) {
    uint32_t u = __builtin_bit_cast(uint32_t, f);
    u += 0x7FFFu + ((u >> 16) & 1u);   // RNE
    return (u16)(u >> 16);
}
__device__ __forceinline__ u32 pk2bf(float a, float b) {
    return (u32)f2bf(a) | ((u32)f2bf(b) << 16);
}

// async global->LDS, 16B per lane. LDS dest must be wave-uniform base + lane*16.
__device__ __forceinline__ void async_cp16(const u16* gsrc, u16* ldst) {
    __builtin_amdgcn_global_load_lds(
        (__attribute__((address_space(1))) void*)(gsrc),
        (__attribute__((address_space(3))) void*)(ldst), 16, 0, 0);
}

// ---------------- fused: headw+x-cast | Wq/Wkv cast | rope cos/sin table ----------------
// R10: cvt_hw reverted to the R8-measured form (286.5 us best run). R9's register-gate
// variant measured +3.6 us — keep the winner. Wo cast lives in gemm_qkv's idle blocks.
constexpr int HWB = Mc;                   // 4096 headw(+x cast) blocks
constexpr int CQ1 = DIMc * DIMc / 4;      // Wq quads
constexpr int CQ2 = 1024 * DIMc / 4;      // Wkv quads
constexpr int NWQ = (CQ1 + CQ2) / 256;    // 6144 weight-cast blocks (Wo moved out)
constexpr int NTB = Sc * 64 / 256;        // 512 rope-table blocks
__global__ __launch_bounds__(256) void cvt_hw(const float* __restrict__ x,
                                              const float* __restrict__ Wq,
                                              const float* __restrict__ Wkv,
                                              const float* __restrict__ Wr,
                                              const float* __restrict__ br,
                                              u16* __restrict__ xb,
                                              u16* __restrict__ Wqkvb,
                                              float* __restrict__ hw,
                                              float2* __restrict__ csT) {
    __shared__ __align__(16) float xs[2048];
    int bid = blockIdx.x;
    if (bid < HWB) {
        // head gate + x row cast (x read once, staged in LDS) — fully float4-vectorized
        const int m = bid;
        const float4* xg = (const float4*)(x + (size_t)m * 2048);
        float4* xs4 = (float4*)xs;
        for (int i = threadIdx.x; i < 512; i += 256) xs4[i] = xg[i];
        __syncthreads();
        {
            ushort4* dst = (ushort4*)(xb + (size_t)m * 2048);
            for (int i = threadIdx.x; i < 512; i += 256) {
                float4 v = xs4[i];
                ushort4 o;
                o.x = f2bf(v.x); o.y = f2bf(v.y); o.z = f2bf(v.z); o.w = f2bf(v.w);
                dst[i] = o;
            }
        }
        const int wid = threadIdx.x >> 6, lane = threadIdx.x & 63;
#pragma unroll 1
        for (int h = wid; h < NHc; h += 4) {
            const float4* wr4 = (const float4*)(Wr + (size_t)h * 2048);
            float s = 0.f;
#pragma unroll
            for (int j = 0; j < 8; j++) {
                float4 xv = xs4[lane + j * 64];
                float4 wv = wr4[lane + j * 64];
                s += xv.x * wv.x + xv.y * wv.y + xv.z * wv.z + xv.w * wv.w;
            }
#pragma unroll
            for (int off = 32; off; off >>= 1) s += __shfl_xor(s, off, 64);
            if (lane == 0) hw[m * NHc + h] = 1.f / (1.f + __expf(-(s + br[h])));
        }
        return;
    }
    bid -= HWB;
    if (bid < NWQ) {
        int q = bid * 256 + threadIdx.x;
        const float* src; u16* dst; int qi;
        if (q < CQ1) { src = Wq;  dst = Wqkvb; qi = q; }
        else         { src = Wkv; dst = Wqkvb + (size_t)DIMc * DIMc; qi = q - CQ1; }
        float4 v = ((const float4*)src)[qi];
        ushort4 o;
        o.x = f2bf(v.x); o.y = f2bf(v.y); o.z = f2bf(v.z); o.w = f2bf(v.w);
        ((ushort4*)dst)[qi] = o;
        return;
    }
    bid -= NWQ;
    // rope table: csT[s*64+d] = {cos, sin}(s * 10000^(-d/64)) — matches reference math
    int idx = bid * 256 + threadIdx.x;
    int s = idx >> 6, d = idx & 63;
    float invf = powf(10000.0f, -(float)d * (1.0f / 64.0f));
    float ang = (float)s * invf;
    float2 cs;
    cs.x = cosf(ang);
    cs.y = sinf(ang);
    csT[idx] = cs;
}

// ---------------- QKV GEMM: 256x256 tile, 8-phase counted-vmcnt schedule (R4/R5) ----
// 1D grid 256 blocks = full chip: blocks 0..191 = GEMM tiles (n = bid%12, m = bid/12);
// blocks 192..255 cast Wo->bf16 in the GEMM's shadow (Wob consumed only by gemm_bt4,
// two launches later, same stream). K-loop byte-identical to the R4/R5-verified 8-phase
// counted-vmcnt schedule; epilogue fully unrolled (rule #20).
__global__ __launch_bounds__(512, 2) void gemm_qkv(const u16* __restrict__ A,
                                                   const u16* __restrict__ Bw,
                                                   const float* __restrict__ hw,
                                                   const float2* __restrict__ csT,
                                                   const float* __restrict__ Wo,
                                                   u16* __restrict__ Wob,
                                                   u16* __restrict__ Qr,
                                                   u16* __restrict__ Kb,
                                                   u16* __restrict__ Vt,
                                                   u16* __restrict__ Vg) {
    const int bidL = blockIdx.x;
    if (bidL >= 192) {
        // Wo cast: 64 blocks x 512 threads x 32 float4 = 1M quads
        const float4* src = (const float4*)Wo;
        ushort4* dst = (ushort4*)Wob;
        int i0 = (bidL - 192) * 16384 + threadIdx.x;
#pragma unroll
        for (int k = 0; k < 32; k++) {
            float4 v = src[i0 + k * 512];
            ushort4 o;
            o.x = f2bf(v.x); o.y = f2bf(v.y); o.z = f2bf(v.z); o.w = f2bf(v.w);
            dst[i0 + k * 512] = o;
        }
        return;
    }
    __shared__ __align__(16) u16 SM[4][2][128 * 64];   // 131072 B
    float* EpS = (float*)SM;                           // 64*261*4 = 66816 B, aliased
    const int Kd = DIMc;
    constexpr int NT = 32;                             // K-tiles
    const int tid  = threadIdx.x;
    const int lane = tid & 63;
    const int wid  = tid >> 6;
    const int m0 = (bidL / 12) * 256;
    const int n0 = (bidL % 12) * 256;
    const int wr = wid >> 2;            // 0..1 (M)
    const int wc = wid & 3;             // 0..3 (N)
    const int fr = lane & 15;
    const int fq = lane >> 4;
    const int f7 = fr & 7;

    // staging addresses: per half-tile, thread does 2 loads (slots tid, tid+512)
    const int s0 = tid, s1 = tid + 512;
    const int r0 = s0 >> 3, r1 = s1 >> 3;             // 0..127 row within half
    const int j0 = (s0 & 7) ^ (r0 & 7), j1 = (s1 & 7) ^ (r1 & 7);  // pre-swizzled src chunk
    const u16* gA0 = A  + (size_t)(m0 + r0) * Kd + j0 * 8;
    const u16* gA1 = A  + (size_t)(m0 + r1) * Kd + j1 * 8;
    const u16* gB0 = Bw + (size_t)(n0 + r0) * Kd + j0 * 8;
    const u16* gB1 = Bw + (size_t)(n0 + r1) * Kd + j1 * 8;
    const size_t hK = (size_t)128 * Kd;

    auto stA = [&](int buf, int h, int t) {
        async_cp16(gA0 + h * hK + t * 64, &SM[buf][h][s0 * 8]);
        async_cp16(gA1 + h * hK + t * 64, &SM[buf][h][s1 * 8]);
    };
    auto stB = [&](int buf, int h, int t) {
        async_cp16(gB0 + h * hK + t * 64, &SM[2 + buf][h][s0 * 8]);
        async_cp16(gB1 + h * hK + t * 64, &SM[2 + buf][h][s1 * 8]);
    };

    f32x4 acc[8][4];
#pragma unroll
    for (int i = 0; i < 8; i++)
#pragma unroll
        for (int j = 0; j < 4; j++) {
            f32x4 z = {0.f, 0.f, 0.f, 0.f};
            acc[i][j] = z;
        }

    const int c0 = ((fq) ^ f7) * 8;       // ks=0 chunk offset (u16 units)
    const int c1 = ((4 + fq) ^ f7) * 8;   // ks=1 chunk
    bf16x8 afl[4][2], afh[4][2], bfl[2][2], bfh[2][2];

    auto rdA = [&](bf16x8 (&af)[4][2], int tb, int mh) {
        const u16* Ab = SM[tb][wr];       // wave wr reads only A-half wr
#pragma unroll
        for (int m2 = 0; m2 < 4; m2++) {
            int row = (mh * 4 + m2) * 16 + fr;
            af[m2][0] = __builtin_bit_cast(bf16x8, *(const u16x8*)(Ab + row * 64 + c0));
            af[m2][1] = __builtin_bit_cast(bf16x8, *(const u16x8*)(Ab + row * 64 + c1));
        }
    };
    auto rdB = [&](bf16x8 (&bf)[2][2], int tb, int nh) {
        const u16* Bb = SM[2 + tb][wc >> 1];   // wave wc reads only B-half wc>>1
#pragma unroll
        for (int n2 = 0; n2 < 2; n2++) {
            int row = (wc & 1) * 64 + (nh * 2 + n2) * 16 + fr;
            bf[n2][0] = __builtin_bit_cast(bf16x8, *(const u16x8*)(Bb + row * 64 + c0));
            bf[n2][1] = __builtin_bit_cast(bf16x8, *(const u16x8*)(Bb + row * 64 + c1));
        }
    };
    auto mma = [&](bf16x8 (&af)[4][2], bf16x8 (&bf)[2][2], int mh, int nh) {
        __builtin_amdgcn_s_setprio(1);
#pragma unroll
        for (int m2 = 0; m2 < 4; m2++)
#pragma unroll
            for (int n2 = 0; n2 < 2; n2++) {
                acc[mh * 4 + m2][nh * 2 + n2] =
                    __builtin_amdgcn_mfma_f32_16x16x32_bf16(af[m2][0], bf[n2][0],
                                                            acc[mh * 4 + m2][nh * 2 + n2], 0, 0, 0);
                acc[mh * 4 + m2][nh * 2 + n2] =
                    __builtin_amdgcn_mfma_f32_16x16x32_bf16(af[m2][1], bf[n2][1],
                                                            acc[mh * 4 + m2][nh * 2 + n2], 0, 0, 0);
            }
        __builtin_amdgcn_s_setprio(0);
    };

#define LGK0 do { asm volatile("s_waitcnt lgkmcnt(0)" ::: "memory"); \
                  __builtin_amdgcn_sched_barrier(0); } while (0)
#define BAR  __builtin_amdgcn_s_barrier()

    // prologue: tile0 (A,B) + tile1 B halves = 12 loads; drain to tile0 complete
    stA(0, 0, 0); stA(0, 1, 0); stB(0, 0, 0); stB(0, 1, 0);
    stB(1, 0, 1); stB(1, 1, 1);
    asm volatile("s_waitcnt vmcnt(4)" ::: "memory");
    BAR;

#pragma unroll 1
    for (int i = 0; i < NT / 2; i++) {
        const int t0 = 2 * i, t1 = 2 * i + 1;
        // ---- ph1: tile t0 quadrant (0,0) ----
        rdA(afl, 0, 0); rdB(bfl, 0, 0);
        stA(1, 0, t1);
        BAR; LGK0; mma(afl, bfl, 0, 0); BAR;
        // ---- ph2: (0,1) ----
        rdB(bfh, 0, 1);
        stA(1, 1, t1);
        BAR; LGK0; mma(afl, bfh, 0, 1); BAR;
        // ---- ph3: (1,0) ----
        rdA(afh, 0, 1);
        if (t0 + 2 < NT) stB(0, 0, t0 + 2);
        BAR; LGK0; mma(afh, bfl, 1, 0); BAR;
        // ---- ph4: (1,1); counted vmcnt ----
        if (t0 + 2 < NT) {
            stB(0, 1, t0 + 2);
            asm volatile("s_waitcnt vmcnt(4)" ::: "memory");   // t1 fully landed; 2 halves fly
        } else {
            asm volatile("s_waitcnt vmcnt(0)" ::: "memory");   // tail
        }
        BAR; __builtin_amdgcn_sched_barrier(0); mma(afh, bfh, 1, 1); BAR;
        // ---- ph5: tile t1 quadrant (0,0) ----
        rdA(afl, 1, 0); rdB(bfl, 1, 0);
        if (t0 + 2 < NT) stA(0, 0, t0 + 2);
        BAR; LGK0; mma(afl, bfl, 0, 0); BAR;
        // ---- ph6: (0,1) ----
        rdB(bfh, 1, 1);
        if (t0 + 2 < NT) stA(0, 1, t0 + 2);
        BAR; LGK0; mma(afl, bfh, 0, 1); BAR;
        // ---- ph7: (1,0) ----
        rdA(afh, 1, 1);
        if (t1 + 2 < NT) stB(1, 0, t1 + 2);
        BAR; LGK0; mma(afh, bfl, 1, 0); BAR;
        // ---- ph8: (1,1); counted vmcnt ----
        if (t1 + 2 < NT) {
            stB(1, 1, t1 + 2);
            asm volatile("s_waitcnt vmcnt(4)" ::: "memory");   // t0+2 fully landed
        } else {
            asm volatile("s_waitcnt vmcnt(0)" ::: "memory");   // tail: drains everything
        }
        BAR; __builtin_amdgcn_sched_barrier(0); mma(afh, bfh, 1, 1); BAR;
    }
#undef LGK0
#undef BAR

    // ---- fused epilogue: 4 passes of 64 rows x 256 cols (2 heads). FULLY UNROLLED so
    // acc indices are static (rule #20) — p, m2, nj, r all compile-time constants. ----
    const int tL = n0 >> 7;                // even; heads tL, tL+1 (same kind)
    const int bb = m0 >> 11;               // batch (256-row tile never crosses)
    const int sb_t = m0 & 2047;
#pragma unroll
    for (int p = 0; p < 4; p++) {
        __syncthreads();                   // prior pass / K-loop reads done
        if (wr == (p >> 1)) {
#pragma unroll
            for (int m2 = 0; m2 < 4; m2++) {
#pragma unroll
                for (int nj = 0; nj < 4; nj++) {
                    int lr = m2 * 16 + fq * 4;
                    int col = wc * 64 + nj * 16 + fr;
#pragma unroll
                    for (int r = 0; r < 4; r++)
                        EpS[(lr + r) * 261 + col] = acc[(p & 1) * 4 + m2][nj][r];
                }
            }
        }
        __syncthreads();
        const int sbase = sb_t + p * 64;
        if (tL < 20) {
            // rope path (Q: gate+scale; K: plain), both heads of this tile
            const int d = tid & 63, rg = tid >> 6;
#pragma unroll 1
            for (int ch = 0; ch < 2; ch++) {
                const int t = tL + ch;
#pragma unroll
                for (int tt = 0; tt < 8; tt++) {
                    int lr = rg + 8 * tt;
                    int s = sbase + lr;
                    float v1 = EpS[lr * 261 + ch * 128 + d];
                    float v2 = EpS[lr * 261 + ch * 128 + 64 + d];
                    float2 cs = csT[(s << 6) + d];
                    float o1 = v1 * cs.x - v2 * cs.y;
                    float o2 = v2 * cs.x + v1 * cs.y;
                    if (t < 16) {
                        float w = hw[(size_t)((bb << 11) + s) * NHc + t] * SCALE;
                        size_t g = ((size_t)(bb * NHc + t) << 11) + s;
                        Qr[g * HDc + d]      = f2bf(o1 * w);
                        Qr[g * HDc + 64 + d] = f2bf(o2 * w);
                    } else {
                        size_t g = ((size_t)(bb * NKVc + (t - 16)) << 11) + s;
                        Kb[g * HDc + d]      = f2bf(o1);
                        Kb[g * HDc + 64 + d] = f2bf(o2);
                    }
                }
            }
        } else {
            // V transpose path + strided global-V gather, both heads
            const int sl = tid & 63, dg = tid >> 6;
            const int sg = sbase + sl;
#pragma unroll 1
            for (int ch = 0; ch < 2; ch++) {
                const int bhv = bb * NKVc + (tL + ch - 20);
                u16* Vbase = Vt + (size_t)bhv * HDc * Sc;
#pragma unroll
                for (int tt = 0; tt < 16; tt++) {
                    int d = dg + 8 * tt;
                    u16 bv = f2bf(EpS[sl * 261 + ch * 128 + d]);
                    Vbase[(size_t)d * Sc + sg] = bv;
                    if ((sg & 63) == 0)
                        Vg[(size_t)bhv * 4096 + d * 32 + (sg >> 6)] = bv;
                }
            }
        }
    }
}

// ---------------- bf16 GEMM (O-proj): 256x128 tile, 8-phase counted-vmcnt (R10) ----
// C[M,N] = A[M,K] * W[N,K]^T (fp32 out). 512 threads = 8 waves (2M x 4N), wave tile
// 128x32, acc[8][2]. Port of the qkv-validated 8-phase fine interleave to bt geometry
// (4-phase bt3 measured-class ~565 TF; 8-phase qkv = 650 TF).
// LDS 96 KB: SA[2buf][2 row-halves][128x64], SB[2buf][128x64]. 3 staging units/tile
// (A-h0, A-h1, B; 2 loads each). vmcnt FIFO (in loads): prologue [A0(0),A1(0),B(0),B(1)]
// -> vmcnt(2) leaves B(1); steady ph4/ph8 have 8 outstanding, vmcnt(2) leaves exactly
// the newest unit (next tile's B) while the upcoming tile's 3 units are landed.
// Tails: guards degrade to vmcnt(0). Buffer overwrite per unit checked against its
// last-reader phase barrier (same invariant as qkv's 8-phase).
__global__ __launch_bounds__(512, 2) void gemm_bt4(const u16* __restrict__ A,
                                                   const u16* __restrict__ Bw,
                                                   float* __restrict__ C,
                                                   int Mdim, int Ndim, int Kdim) {
    __shared__ __align__(16) u16 SA[2][2][128 * 64];   // 64 KB
    __shared__ __align__(16) u16 SB[2][128 * 64];      // 32 KB
    const int NT = Kdim >> 6;                          // 32
    const int tid  = threadIdx.x;
    const int lane = tid & 63;
    const int wid  = tid >> 6;
    const int m0 = blockIdx.y * 256;
    const int n0 = blockIdx.x * 128;
    const int wr = wid >> 2;            // 0..1 (M half, 128 rows)
    const int wc = wid & 3;             // 0..3 (N quarter, 32 cols)
    const int fr = lane & 15;
    const int fq = lane >> 4;
    const int f7 = fr & 7;

    // staging: thread's 2 slots per 128x64 half-tile (rows r0 in [0,64), r1 in [64,128))
    const int s0 = tid, s1 = tid + 512;
    const int r0 = s0 >> 3, r1 = s1 >> 3;
    const int j0 = (s0 & 7) ^ (r0 & 7), j1 = (s1 & 7) ^ (r1 & 7);
    const u16* gA0 = A  + (size_t)(m0 + r0) * Kdim + j0 * 8;
    const u16* gA1 = A  + (size_t)(m0 + r1) * Kdim + j1 * 8;
    const u16* gB0 = Bw + (size_t)(n0 + r0) * Kdim + j0 * 8;
    const u16* gB1 = Bw + (size_t)(n0 + r1) * Kdim + j1 * 8;
    const size_t hK = (size_t)128 * Kdim;

    auto stA = [&](int buf, int h, int t) {
        async_cp16(gA0 + h * hK + t * 64, &SA[buf][h][s0 * 8]);
        async_cp16(gA1 + h * hK + t * 64, &SA[buf][h][s1 * 8]);
    };
    auto stB = [&](int buf, int t) {
        async_cp16(gB0 + t * 64, &SB[buf][s0 * 8]);
        async_cp16(gB1 + t * 64, &SB[buf][s1 * 8]);
    };

    f32x4 acc[8][2];
#pragma unroll
    for (int i = 0; i < 8; i++)
#pragma unroll
        for (int j = 0; j < 2; j++) {
            f32x4 z = {0.f, 0.f, 0.f, 0.f};
            acc[i][j] = z;
        }

    const int c0 = ((fq) ^ f7) * 8;       // ks=0 chunk offset (u16 units)
    const int c1 = ((4 + fq) ^ f7) * 8;   // ks=1 chunk
    bf16x8 afl[4][2], afh[4][2], bfl[2], bfh[2];

    auto rdA = [&](bf16x8 (&af)[4][2], int tb, int mh) {
        const u16* Ab = SA[tb][wr];       // wave wr reads only its row-half
#pragma unroll
        for (int m2 = 0; m2 < 4; m2++) {
            int row = (mh * 4 + m2) * 16 + fr;
            af[m2][0] = __builtin_bit_cast(bf16x8, *(const u16x8*)(Ab + row * 64 + c0));
            af[m2][1] = __builtin_bit_cast(bf16x8, *(const u16x8*)(Ab + row * 64 + c1));
        }
    };
    auto rdB = [&](bf16x8 (&bf)[2], int tb, int nh) {
        const u16* Bb = SB[tb];
        int row = wc * 32 + nh * 16 + fr;
        bf[0] = __builtin_bit_cast(bf16x8, *(const u16x8*)(Bb + row * 64 + c0));
        bf[1] = __builtin_bit_cast(bf16x8, *(const u16x8*)(Bb + row * 64 + c1));
    };
    auto mma = [&](bf16x8 (&af)[4][2], bf16x8 (&bf)[2], int mh, int nh) {
        __builtin_amdgcn_s_setprio(1);
#pragma unroll
        for (int m2 = 0; m2 < 4; m2++) {
            acc[mh * 4 + m2][nh] = __builtin_amdgcn_mfma_f32_16x16x32_bf16(
                af[m2][0], bf[0], acc[mh * 4 + m2][nh], 0, 0, 0);
            acc[mh * 4 + m2][nh] = __builtin_amdgcn_mfma_f32_16x16x32_bf16(
                af[m2][1], bf[1], acc[mh * 4 + m2][nh], 0, 0, 0);
        }
        __builtin_amdgcn_s_setprio(0);
    };

#define LGK0 do { asm volatile("s_waitcnt lgkmcnt(0)" ::: "memory"); \
                  __builtin_amdgcn_sched_barrier(0); } while (0)
#define BAR  __builtin_amdgcn_s_barrier()

    // prologue: tile0 (A0,A1,B) + tile1 B = 8 loads; vmcnt(2) -> tile0 landed, B(1) flies
    stA(0, 0, 0); stA(0, 1, 0); stB(0, 0);
    stB(1, 1);
    asm volatile("s_waitcnt vmcnt(2)" ::: "memory");
    BAR;

#pragma unroll 1
    for (int i = 0; i < NT / 2; i++) {
        const int t0 = 2 * i, t1 = 2 * i + 1;
        // ---- ph1: tile t0 quadrant (0,0) ----
        rdA(afl, 0, 0); rdB(bfl, 0, 0);
        stA(1, 0, t1);
        BAR; LGK0; mma(afl, bfl, 0, 0); BAR;
        // ---- ph2: (0,1) ----
        rdB(bfh, 0, 1);
        stA(1, 1, t1);
        BAR; LGK0; mma(afl, bfh, 0, 1); BAR;
        // ---- ph3: (1,0) ----
        rdA(afh, 0, 1);
        if (t0 + 2 < NT) stB(0, t0 + 2);
        BAR; LGK0; mma(afh, bfl, 1, 0); BAR;
        // ---- ph4: (1,1); counted vmcnt: t1's B+A0+A1 landed, B(t0+2) flies ----
        if (t0 + 2 < NT) {
            asm volatile("s_waitcnt vmcnt(2)" ::: "memory");
        } else {
            asm volatile("s_waitcnt vmcnt(0)" ::: "memory");   // tail
        }
        BAR; __builtin_amdgcn_sched_barrier(0); mma(afh, bfh, 1, 1); BAR;
        // ---- ph5: tile t1 quadrant (0,0) ----
        rdA(afl, 1, 0); rdB(bfl, 1, 0);
        if (t0 + 2 < NT) stA(0, 0, t0 + 2);
        BAR; LGK0; mma(afl, bfl, 0, 0); BAR;
        // ---- ph6: (0,1) ----
        rdB(bfh, 1, 1);
        if (t0 + 2 < NT) stA(0, 1, t0 + 2);
        BAR; LGK0; mma(afl, bfh, 0, 1); BAR;
        // ---- ph7: (1,0) ----
        rdA(afh, 1, 1);
        if (t1 + 2 < NT) stB(1, t1 + 2);
        BAR; LGK0; mma(afh, bfl, 1, 0); BAR;
        // ---- ph8: (1,1); counted vmcnt: t0+2's B+A0+A1 landed, B(t1+2) flies ----
        if (t1 + 2 < NT) {
            asm volatile("s_waitcnt vmcnt(2)" ::: "memory");
        } else {
            asm volatile("s_waitcnt vmcnt(0)" ::: "memory");   // tail: drains everything
        }
        BAR; __builtin_amdgcn_sched_barrier(0); mma(afh, bfh, 1, 1); BAR;
    }
#undef LGK0
#undef BAR

    // ---- epilogue: fp32 C write (verified frag C/D mapping; wave offsets wr*128/wc*32) ----
#pragma unroll
    for (int i = 0; i < 8; i++)
#pragma unroll
        for (int j = 0; j < 2; j++) {
            int row = m0 + wr * 128 + i * 16 + fq * 4;
            int col = n0 + wc * 32 + j * 16 + fr;
#pragma unroll
            for (int r = 0; r < 4; r++)
                C[(size_t)(row + r) * Ndim + col] = acc[i][j][r];
        }
}

// ---------------- MFMA flash attention helpers ----------------
__device__ __forceinline__ float colreduce_max(f32x4 a, f32x4 b) {
    float m = fmaxf(fmaxf(fmaxf(a[0], a[1]), fmaxf(a[2], a[3])),
                    fmaxf(fmaxf(b[0], b[1]), fmaxf(b[2], b[3])));
    m = fmaxf(m, __shfl_xor(m, 16, 64));
    m = fmaxf(m, __shfl_xor(m, 32, 64));
    return m;
}

// exp(S^T) C-frags -> B-operand frag (K=32) for mfma_f32_16x16x32_bf16, via shuffles
__device__ __forceinline__ bf16x8 build_pfrag(u32 pk0, u32 pk1, u32 pk2, u32 pk3, int lane) {
    const int c = lane & 15, Q = lane >> 4;
    const int sl0 = ((Q & 1) * 2) * 16 + c;
    const int sl1 = sl0 + 16;
    u32 a0 = (u32)__shfl((int)pk0, sl0, 64), b0 = (u32)__shfl((int)pk2, sl0, 64);
    u32 a1 = (u32)__shfl((int)pk1, sl0, 64), b1 = (u32)__shfl((int)pk3, sl0, 64);
    u32 a2 = (u32)__shfl((int)pk0, sl1, 64), b2 = (u32)__shfl((int)pk2, sl1, 64);
    u32 a3 = (u32)__shfl((int)pk1, sl1, 64), b3 = (u32)__shfl((int)pk3, sl1, 64);
    const bool hi = Q >= 2;
    u32x4v r = { hi ? b0 : a0, hi ? b1 : a1, hi ? b2 : a2, hi ? b3 : a3 };
    return __builtin_bit_cast(bf16x8, r);
}

// ---------------- attn3: 256-thread blocks, 64 queries, LDS-staged K/V double buffer ----
__global__ __launch_bounds__(256) void attn3(const u16* __restrict__ Qr,
                                             const u16* __restrict__ Kb,
                                             const u16* __restrict__ Vt,
                                             const u16* __restrict__ Vg,
                                             u16* __restrict__ attnb) {
    __shared__ __align__(16) u16 Ksh[2 * 4096];
    __shared__ __align__(16) u16 Vsh[2 * 4096];
    const int tid  = threadIdx.x;
    const int lane = tid & 63, wid = tid >> 6;
    const int bid  = blockIdx.x;                   // 0..1023
    const int q64  = (31 - (bid >> 5)) << 6;       // heavy blocks dispatched first
    const int bh   = bid & 31;
    const int h    = bh & 15;
    const int b    = bh >> 4;
    const int qw   = q64 + wid * 16;
    const int c = lane & 15, Q = lane >> 4;
    const int kvh = h >> 2;

    const u16* Qp = Qr + ((size_t)((b * NHc + h) * Sc + qw)) * HDc;
    const u16* Kh = Kb + (size_t)(b * NKVc + kvh) * Sc * HDc;
    const u16* Vh = Vt + (size_t)(b * NKVc + kvh) * HDc * Sc;
    const u16* Vgh = Vg + (size_t)(b * NKVc + kvh) * HDc * 32;

    const int kp0 = (q64 >= 256) ? (q64 - 256) : 0;
    const int nstages = (q64 + 64 - kp0) >> 5;     // <= 10

    auto stageLoad = [&](int bufi, int kp) {
        u16* Kd = Ksh + bufi * 4096;
        u16* Vd = Vsh + bufi * 4096;
#pragma unroll
        for (int qq = 0; qq < 2; qq++) {
            int s = tid + qq * 256;
            int kr = s >> 4;
            int jk = (s & 15) ^ (kr & 15);
            async_cp16(Kh + (size_t)(kp + kr) * HDc + jk * 8, Kd + s * 8);
            int dv = s >> 2;
            int jv = (s & 3) ^ ((dv >> 2) & 3);
            async_cp16(Vh + (size_t)dv * Sc + kp + jv * 8, Vd + s * 8);
        }
    };

    bf16x8 qf[4];
#pragma unroll
    for (int ch = 0; ch < 4; ch++)
        qf[ch] = __builtin_bit_cast(bf16x8, *(const u16x8*)(Qp + c * HDc + ch * 32 + Q * 8));

    stageLoad(0, kp0);   // prologue

    // ---- global branch: 32 strided keys, unmasked, exact softmax ----
    f32x4 sg0 = {0.f,0.f,0.f,0.f}, sg1 = {0.f,0.f,0.f,0.f};
#pragma unroll
    for (int ch = 0; ch < 4; ch++) {
        bf16x8 k0 = __builtin_bit_cast(bf16x8, *(const u16x8*)(Kh + ((size_t)c << 6) * HDc + ch * 32 + Q * 8));
        bf16x8 k1 = __builtin_bit_cast(bf16x8, *(const u16x8*)(Kh + ((size_t)(c + 16) << 6) * HDc + ch * 32 + Q * 8));
        sg0 = __builtin_amdgcn_mfma_f32_16x16x32_bf16(k0, qf[ch], sg0, 0, 0, 0);
        sg1 = __builtin_amdgcn_mfma_f32_16x16x32_bf16(k1, qf[ch], sg1, 0, 0, 0);
    }
    float mg = colreduce_max(sg0, sg1);
    f32x4 pg0, pg1;
    float gsum = 0.f;
#pragma unroll
    for (int r = 0; r < 4; r++) {
        pg0[r] = __expf(sg0[r] - mg);
        pg1[r] = __expf(sg1[r] - mg);
        gsum += pg0[r] + pg1[r];
    }
    gsum += __shfl_xor(gsum, 16, 64);
    gsum += __shfl_xor(gsum, 32, 64);
    const float lG = gsum;
    bf16x8 pgf = build_pfrag(pk2bf(pg0[0], pg0[1]), pk2bf(pg0[2], pg0[3]),
                             pk2bf(pg1[0], pg1[1]), pk2bf(pg1[2], pg1[3]), lane);
    f32x4 OG[8];
#pragma unroll
    for (int dt = 0; dt < 8; dt++) {
        bf16x8 vf = __builtin_bit_cast(bf16x8, *(const u16x8*)(Vgh + (dt * 16 + c) * 32 + Q * 8));
        f32x4 z = {0.f, 0.f, 0.f, 0.f};
        OG[dt] = __builtin_amdgcn_mfma_f32_16x16x32_bf16(vf, pgf, z, 0, 0, 0);
    }

    // ---- local branch: window [q-256, q], online softmax over LDS-staged stages ----
    f32x4 OL[8];
#pragma unroll
    for (int dt = 0; dt < 8; dt++) { f32x4 z = {0.f,0.f,0.f,0.f}; OL[dt] = z; }
    float mL = -1e30f, lL = 0.f;

    for (int ip = 0; ip < nstages; ip++) {
        const int kp = kp0 + ip * 32;
        __syncthreads();
        if (ip + 1 < nstages) stageLoad((ip + 1) & 1, kp + 32);
        const u16* Kd = Ksh + (ip & 1) * 4096;
        const u16* Vd = Vsh + (ip & 1) * 4096;

        if (kp > qw + 15 || kp + 31 < qw - 256) continue;   // wave-uniform skip

        f32x4 s0 = {0.f,0.f,0.f,0.f}, s1 = {0.f,0.f,0.f,0.f};
#pragma unroll
        for (int ch = 0; ch < 4; ch++) {
            int jj = ch * 4 + Q;
            bf16x8 k0 = __builtin_bit_cast(bf16x8, *(const u16x8*)(Kd + (c * 16 + (jj ^ c)) * 8));
            bf16x8 k1 = __builtin_bit_cast(bf16x8, *(const u16x8*)(Kd + ((16 + c) * 16 + (jj ^ c)) * 8));
            s0 = __builtin_amdgcn_mfma_f32_16x16x32_bf16(k0, qf[ch], s0, 0, 0, 0);
            s1 = __builtin_amdgcn_mfma_f32_16x16x32_bf16(k1, qf[ch], s1, 0, 0, 0);
        }
        if ((kp + 31 > qw) || (kp < qw - 241)) {
            const int q = qw + c;
#pragma unroll
            for (int r = 0; r < 4; r++) {
                int kk0 = kp + Q * 4 + r;
                int kk1 = kk0 + 16;
                if (kk0 > q || kk0 + 256 < q) s0[r] = -1e30f;
                if (kk1 > q || kk1 + 256 < q) s1[r] = -1e30f;
            }
        }
        float mx = colreduce_max(s0, s1);
        float mnew = fmaxf(mL, mx);
        float alpha = __expf(mL - mnew);
        f32x4 p0, p1;
        float sum = 0.f;
#pragma unroll
        for (int r = 0; r < 4; r++) {
            p0[r] = __expf(s0[r] - mnew);
            p1[r] = __expf(s1[r] - mnew);
            sum += p0[r] + p1[r];
        }
        sum += __shfl_xor(sum, 16, 64);
        sum += __shfl_xor(sum, 32, 64);
        lL = lL * alpha + sum;
        mL = mnew;
        bf16x8 pf = build_pfrag(pk2bf(p0[0], p0[1]), pk2bf(p0[2], p0[3]),
                                pk2bf(p1[0], p1[1]), pk2bf(p1[2], p1[3]), lane);
#pragma unroll
        for (int dt = 0; dt < 8; dt++) {
            int d = dt * 16 + c;
            bf16x8 vf = __builtin_bit_cast(bf16x8, *(const u16x8*)(Vd + (d * 4 + (Q ^ (c >> 2))) * 8));
            OL[dt] = OL[dt] * alpha;
            OL[dt] = __builtin_amdgcn_mfma_f32_16x16x32_bf16(vf, pf, OL[dt], 0, 0, 0);
        }
    }

    // ---- epilogue: 0.7*local + 0.3*global, write bf16 [B,S,DIM] ----
    const float rL = 0.7f / lL, rG = 0.3f / lG;
    u16* orow = attnb + ((size_t)(b * Sc + qw + c)) * DIMc + h * HDc;
#pragma unroll
    for (int dt = 0; dt < 8; dt++) {
        ushort4 ov;
        ov.x = f2bf(OL[dt][0] * rL + OG[dt][0] * rG);
        ov.y = f2bf(OL[dt][1] * rL + OG[dt][1] * rG);
        ov.z = f2bf(OL[dt][2] * rL + OG[dt][2] * rG);
        ov.w = f2bf(OL[dt][3] * rL + OG[dt][3] * rG);
        *(ushort4*)(orow + dt * 16 + Q * 4) = ov;
    }
}

extern "C" void kernel_launch(void* const* d_in, const int* in_sizes, int n_in,
                              void* d_out, int out_size, void* d_ws, size_t ws_size,
                              hipStream_t stream) {
    const float* x   = (const float*)d_in[0];
    const float* Wq  = (const float*)d_in[1];
    const float* Wkv = (const float*)d_in[2];
    const float* Wo  = (const float*)d_in[3];
    const float* Wr  = (const float*)d_in[4];
    const float* br  = (const float*)d_in[5];
    float* out = (float*)d_out;

    // workspace layout (~98 MB)
    char* p = (char*)d_ws;
    u16* xb    = (u16*)p;   p += (size_t)Mc * DIMc * 2;
    u16* Wqkvb = (u16*)p;   p += (size_t)QKVN * DIMc * 2;    // Wq rows then Wkv rows
    u16* Wob   = (u16*)p;   p += (size_t)DIMc * DIMc * 2;
    float* hw  = (float*)p; p += (size_t)Mc * NHc * 4;
    float2* csT = (float2*)p; p += (size_t)Sc * 64 * 8;      // rope cos/sin table, 1 MB
    u16* Qrb   = (u16*)p;   p += (size_t)Mc * DIMc * 2;
    u16* Kb16  = (u16*)p;   p += (size_t)Bc * NKVc * Sc * HDc * 2;
    u16* Vt16  = (u16*)p;   p += (size_t)Bc * NKVc * HDc * Sc * 2;
    u16* Vg16  = (u16*)p;   p += (size_t)Bc * NKVc * HDc * 32 * 2;
    u16* attnb = (u16*)p;   p += (size_t)Mc * DIMc * 2;

    cvt_hw<<<HWB + NWQ + NTB, 256, 0, stream>>>(x, Wq, Wkv, Wr, br, xb, Wqkvb, hw, csT);

    // 1D grid: 192 GEMM tiles + 64 Wo-cast blocks = 256 = full chip
    gemm_qkv<<<256, 512, 0, stream>>>(xb, Wqkvb, hw, csT, Wo, Wob, Qrb, Kb16, Vt16, Vg16);

    attn3<<<Bc * NHc * (Sc / 64), 256, 0, stream>>>(Qrb, Kb16, Vt16, Vg16, attnb);

    dim3 go(DIMc / 128, Mc / 256);     // (16, 16) = 256 blocks, 512 threads, 1 block/CU
    gemm_bt4<<<go, 512, 0, stream>>>(attnb, Wob, out, Mc, DIMc, DIMc);
}

// Round 12
// 280.072 us; speedup vs baseline: 1.0360x; 1.0134x over previous
//
#include <hip/hip_runtime.h>
#include <stdint.h>

typedef unsigned short u16;
typedef uint32_t u32;
typedef __bf16 bf16x8 __attribute__((ext_vector_type(8)));
typedef u16    u16x8  __attribute__((ext_vector_type(8)));
typedef float  f32x4  __attribute__((ext_vector_type(4)));
typedef u32    u32x4v __attribute__((ext_vector_type(4)));

constexpr int Bc = 2, Sc = 2048, DIMc = 2048, NHc = 16, NKVc = 4, HDc = 128;
constexpr int Mc  = Bc * Sc;          // 4096 rows
constexpr int QKVN = 3072;            // merged Q(2048) + K(512) + V(512) projection cols
constexpr float SCALE = 0.08838834764831845f; // 1/sqrt(128)

__device__ __forceinline__ u16 f2bf(float f) {
    uint32_t u = __builtin_bit_cast(uint32_t, f);
    u += 0x7FFFu + ((u >> 16) & 1u);   // RNE
    return (u16)(u >> 16);
}
__device__ __forceinline__ u32 pk2bf(float a, float b) {
    return (u32)f2bf(a) | ((u32)f2bf(b) << 16);
}

// async global->LDS, 16B per lane. LDS dest must be wave-uniform base + lane*16.
__device__ __forceinline__ void async_cp16(const u16* gsrc, u16* ldst) {
    __builtin_amdgcn_global_load_lds(
        (__attribute__((address_space(1))) void*)(gsrc),
        (__attribute__((address_space(3))) void*)(ldst), 16, 0, 0);
}

// ---------------- fused: headw+x-cast | Wq/Wkv cast | rope cos/sin table ----------------
// R8-measured form (286.5/283.8 us best runs). Wo cast lives in gemm_qkv's idle blocks.
constexpr int HWB = Mc;                   // 4096 headw(+x cast) blocks
constexpr int CQ1 = DIMc * DIMc / 4;      // Wq quads
constexpr int CQ2 = 1024 * DIMc / 4;      // Wkv quads
constexpr int NWQ = (CQ1 + CQ2) / 256;    // 6144 weight-cast blocks (Wo moved out)
constexpr int NTB = Sc * 64 / 256;        // 512 rope-table blocks
__global__ __launch_bounds__(256) void cvt_hw(const float* __restrict__ x,
                                              const float* __restrict__ Wq,
                                              const float* __restrict__ Wkv,
                                              const float* __restrict__ Wr,
                                              const float* __restrict__ br,
                                              u16* __restrict__ xb,
                                              u16* __restrict__ Wqkvb,
                                              float* __restrict__ hw,
                                              float2* __restrict__ csT) {
    __shared__ __align__(16) float xs[2048];
    int bid = blockIdx.x;
    if (bid < HWB) {
        // head gate + x row cast (x read once, staged in LDS) — fully float4-vectorized
        const int m = bid;
        const float4* xg = (const float4*)(x + (size_t)m * 2048);
        float4* xs4 = (float4*)xs;
        for (int i = threadIdx.x; i < 512; i += 256) xs4[i] = xg[i];
        __syncthreads();
        {
            ushort4* dst = (ushort4*)(xb + (size_t)m * 2048);
            for (int i = threadIdx.x; i < 512; i += 256) {
                float4 v = xs4[i];
                ushort4 o;
                o.x = f2bf(v.x); o.y = f2bf(v.y); o.z = f2bf(v.z); o.w = f2bf(v.w);
                dst[i] = o;
            }
        }
        const int wid = threadIdx.x >> 6, lane = threadIdx.x & 63;
#pragma unroll 1
        for (int h = wid; h < NHc; h += 4) {
            const float4* wr4 = (const float4*)(Wr + (size_t)h * 2048);
            float s = 0.f;
#pragma unroll
            for (int j = 0; j < 8; j++) {
                float4 xv = xs4[lane + j * 64];
                float4 wv = wr4[lane + j * 64];
                s += xv.x * wv.x + xv.y * wv.y + xv.z * wv.z + xv.w * wv.w;
            }
#pragma unroll
            for (int off = 32; off; off >>= 1) s += __shfl_xor(s, off, 64);
            if (lane == 0) hw[m * NHc + h] = 1.f / (1.f + __expf(-(s + br[h])));
        }
        return;
    }
    bid -= HWB;
    if (bid < NWQ) {
        int q = bid * 256 + threadIdx.x;
        const float* src; u16* dst; int qi;
        if (q < CQ1) { src = Wq;  dst = Wqkvb; qi = q; }
        else         { src = Wkv; dst = Wqkvb + (size_t)DIMc * DIMc; qi = q - CQ1; }
        float4 v = ((const float4*)src)[qi];
        ushort4 o;
        o.x = f2bf(v.x); o.y = f2bf(v.y); o.z = f2bf(v.z); o.w = f2bf(v.w);
        ((ushort4*)dst)[qi] = o;
        return;
    }
    bid -= NWQ;
    // rope table: csT[s*64+d] = {cos, sin}(s * 10000^(-d/64)) — matches reference math
    int idx = bid * 256 + threadIdx.x;
    int s = idx >> 6, d = idx & 63;
    float invf = powf(10000.0f, -(float)d * (1.0f / 64.0f));
    float ang = (float)s * invf;
    float2 cs;
    cs.x = cosf(ang);
    cs.y = sinf(ang);
    csT[idx] = cs;
}

// ---------------- QKV GEMM: 256x256 tile, 8-phase counted-vmcnt schedule (R4/R5) ----
// 1D grid 256 blocks = full chip: blocks 0..191 = GEMM tiles (n = bid%12, m = bid/12);
// blocks 192..255 cast Wo->bf16 in the GEMM's shadow (Wob consumed only by gemm_bt4,
// two launches later, same stream). K-loop byte-identical to the R4/R5-verified 8-phase
// counted-vmcnt schedule; epilogue fully unrolled (rule #20).
__global__ __launch_bounds__(512, 2) void gemm_qkv(const u16* __restrict__ A,
                                                   const u16* __restrict__ Bw,
                                                   const float* __restrict__ hw,
                                                   const float2* __restrict__ csT,
                                                   const float* __restrict__ Wo,
                                                   u16* __restrict__ Wob,
                                                   u16* __restrict__ Qr,
                                                   u16* __restrict__ Kb,
                                                   u16* __restrict__ Vt,
                                                   u16* __restrict__ Vg) {
    const int bidL = blockIdx.x;
    if (bidL >= 192) {
        // Wo cast: 64 blocks x 512 threads x 32 float4 = 1M quads
        const float4* src = (const float4*)Wo;
        ushort4* dst = (ushort4*)Wob;
        int i0 = (bidL - 192) * 16384 + threadIdx.x;
#pragma unroll
        for (int k = 0; k < 32; k++) {
            float4 v = src[i0 + k * 512];
            ushort4 o;
            o.x = f2bf(v.x); o.y = f2bf(v.y); o.z = f2bf(v.z); o.w = f2bf(v.w);
            dst[i0 + k * 512] = o;
        }
        return;
    }
    __shared__ __align__(16) u16 SM[4][2][128 * 64];   // 131072 B
    float* EpS = (float*)SM;                           // 64*261*4 = 66816 B, aliased
    const int Kd = DIMc;
    constexpr int NT = 32;                             // K-tiles
    const int tid  = threadIdx.x;
    const int lane = tid & 63;
    const int wid  = tid >> 6;
    const int m0 = (bidL / 12) * 256;
    const int n0 = (bidL % 12) * 256;
    const int wr = wid >> 2;            // 0..1 (M)
    const int wc = wid & 3;             // 0..3 (N)
    const int fr = lane & 15;
    const int fq = lane >> 4;
    const int f7 = fr & 7;

    // staging addresses: per half-tile, thread does 2 loads (slots tid, tid+512)
    const int s0 = tid, s1 = tid + 512;
    const int r0 = s0 >> 3, r1 = s1 >> 3;             // 0..127 row within half
    const int j0 = (s0 & 7) ^ (r0 & 7), j1 = (s1 & 7) ^ (r1 & 7);  // pre-swizzled src chunk
    const u16* gA0 = A  + (size_t)(m0 + r0) * Kd + j0 * 8;
    const u16* gA1 = A  + (size_t)(m0 + r1) * Kd + j1 * 8;
    const u16* gB0 = Bw + (size_t)(n0 + r0) * Kd + j0 * 8;
    const u16* gB1 = Bw + (size_t)(n0 + r1) * Kd + j1 * 8;
    const size_t hK = (size_t)128 * Kd;

    auto stA = [&](int buf, int h, int t) {
        async_cp16(gA0 + h * hK + t * 64, &SM[buf][h][s0 * 8]);
        async_cp16(gA1 + h * hK + t * 64, &SM[buf][h][s1 * 8]);
    };
    auto stB = [&](int buf, int h, int t) {
        async_cp16(gB0 + h * hK + t * 64, &SM[2 + buf][h][s0 * 8]);
        async_cp16(gB1 + h * hK + t * 64, &SM[2 + buf][h][s1 * 8]);
    };

    f32x4 acc[8][4];
#pragma unroll
    for (int i = 0; i < 8; i++)
#pragma unroll
        for (int j = 0; j < 4; j++) {
            f32x4 z = {0.f, 0.f, 0.f, 0.f};
            acc[i][j] = z;
        }

    const int c0 = ((fq) ^ f7) * 8;       // ks=0 chunk offset (u16 units)
    const int c1 = ((4 + fq) ^ f7) * 8;   // ks=1 chunk
    bf16x8 afl[4][2], afh[4][2], bfl[2][2], bfh[2][2];

    auto rdA = [&](bf16x8 (&af)[4][2], int tb, int mh) {
        const u16* Ab = SM[tb][wr];       // wave wr reads only A-half wr
#pragma unroll
        for (int m2 = 0; m2 < 4; m2++) {
            int row = (mh * 4 + m2) * 16 + fr;
            af[m2][0] = __builtin_bit_cast(bf16x8, *(const u16x8*)(Ab + row * 64 + c0));
            af[m2][1] = __builtin_bit_cast(bf16x8, *(const u16x8*)(Ab + row * 64 + c1));
        }
    };
    auto rdB = [&](bf16x8 (&bf)[2][2], int tb, int nh) {
        const u16* Bb = SM[2 + tb][wc >> 1];   // wave wc reads only B-half wc>>1
#pragma unroll
        for (int n2 = 0; n2 < 2; n2++) {
            int row = (wc & 1) * 64 + (nh * 2 + n2) * 16 + fr;
            bf[n2][0] = __builtin_bit_cast(bf16x8, *(const u16x8*)(Bb + row * 64 + c0));
            bf[n2][1] = __builtin_bit_cast(bf16x8, *(const u16x8*)(Bb + row * 64 + c1));
        }
    };
    auto mma = [&](bf16x8 (&af)[4][2], bf16x8 (&bf)[2][2], int mh, int nh) {
        __builtin_amdgcn_s_setprio(1);
#pragma unroll
        for (int m2 = 0; m2 < 4; m2++)
#pragma unroll
            for (int n2 = 0; n2 < 2; n2++) {
                acc[mh * 4 + m2][nh * 2 + n2] =
                    __builtin_amdgcn_mfma_f32_16x16x32_bf16(af[m2][0], bf[n2][0],
                                                            acc[mh * 4 + m2][nh * 2 + n2], 0, 0, 0);
                acc[mh * 4 + m2][nh * 2 + n2] =
                    __builtin_amdgcn_mfma_f32_16x16x32_bf16(af[m2][1], bf[n2][1],
                                                            acc[mh * 4 + m2][nh * 2 + n2], 0, 0, 0);
            }
        __builtin_amdgcn_s_setprio(0);
    };

#define LGK0 do { asm volatile("s_waitcnt lgkmcnt(0)" ::: "memory"); \
                  __builtin_amdgcn_sched_barrier(0); } while (0)
#define BAR  __builtin_amdgcn_s_barrier()

    // prologue: tile0 (A,B) + tile1 B halves = 12 loads; drain to tile0 complete
    stA(0, 0, 0); stA(0, 1, 0); stB(0, 0, 0); stB(0, 1, 0);
    stB(1, 0, 1); stB(1, 1, 1);
    asm volatile("s_waitcnt vmcnt(4)" ::: "memory");
    BAR;

#pragma unroll 1
    for (int i = 0; i < NT / 2; i++) {
        const int t0 = 2 * i, t1 = 2 * i + 1;
        // ---- ph1: tile t0 quadrant (0,0) ----
        rdA(afl, 0, 0); rdB(bfl, 0, 0);
        stA(1, 0, t1);
        BAR; LGK0; mma(afl, bfl, 0, 0); BAR;
        // ---- ph2: (0,1) ----
        rdB(bfh, 0, 1);
        stA(1, 1, t1);
        BAR; LGK0; mma(afl, bfh, 0, 1); BAR;
        // ---- ph3: (1,0) ----
        rdA(afh, 0, 1);
        if (t0 + 2 < NT) stB(0, 0, t0 + 2);
        BAR; LGK0; mma(afh, bfl, 1, 0); BAR;
        // ---- ph4: (1,1); counted vmcnt ----
        if (t0 + 2 < NT) {
            stB(0, 1, t0 + 2);
            asm volatile("s_waitcnt vmcnt(4)" ::: "memory");   // t1 fully landed; 2 halves fly
        } else {
            asm volatile("s_waitcnt vmcnt(0)" ::: "memory");   // tail
        }
        BAR; __builtin_amdgcn_sched_barrier(0); mma(afh, bfh, 1, 1); BAR;
        // ---- ph5: tile t1 quadrant (0,0) ----
        rdA(afl, 1, 0); rdB(bfl, 1, 0);
        if (t0 + 2 < NT) stA(0, 0, t0 + 2);
        BAR; LGK0; mma(afl, bfl, 0, 0); BAR;
        // ---- ph6: (0,1) ----
        rdB(bfh, 1, 1);
        if (t0 + 2 < NT) stA(0, 1, t0 + 2);
        BAR; LGK0; mma(afl, bfh, 0, 1); BAR;
        // ---- ph7: (1,0) ----
        rdA(afh, 1, 1);
        if (t1 + 2 < NT) stB(1, 0, t1 + 2);
        BAR; LGK0; mma(afh, bfl, 1, 0); BAR;
        // ---- ph8: (1,1); counted vmcnt ----
        if (t1 + 2 < NT) {
            stB(1, 1, t1 + 2);
            asm volatile("s_waitcnt vmcnt(4)" ::: "memory");   // t0+2 fully landed
        } else {
            asm volatile("s_waitcnt vmcnt(0)" ::: "memory");   // tail: drains everything
        }
        BAR; __builtin_amdgcn_sched_barrier(0); mma(afh, bfh, 1, 1); BAR;
    }
#undef LGK0
#undef BAR

    // ---- fused epilogue: 4 passes of 64 rows x 256 cols (2 heads). FULLY UNROLLED so
    // acc indices are static (rule #20) — p, m2, nj, r all compile-time constants. ----
    const int tL = n0 >> 7;                // even; heads tL, tL+1 (same kind)
    const int bb = m0 >> 11;               // batch (256-row tile never crosses)
    const int sb_t = m0 & 2047;
#pragma unroll
    for (int p = 0; p < 4; p++) {
        __syncthreads();                   // prior pass / K-loop reads done
        if (wr == (p >> 1)) {
#pragma unroll
            for (int m2 = 0; m2 < 4; m2++) {
#pragma unroll
                for (int nj = 0; nj < 4; nj++) {
                    int lr = m2 * 16 + fq * 4;
                    int col = wc * 64 + nj * 16 + fr;
#pragma unroll
                    for (int r = 0; r < 4; r++)
                        EpS[(lr + r) * 261 + col] = acc[(p & 1) * 4 + m2][nj][r];
                }
            }
        }
        __syncthreads();
        const int sbase = sb_t + p * 64;
        if (tL < 20) {
            // rope path (Q: gate+scale; K: plain), both heads of this tile
            const int d = tid & 63, rg = tid >> 6;
#pragma unroll 1
            for (int ch = 0; ch < 2; ch++) {
                const int t = tL + ch;
#pragma unroll
                for (int tt = 0; tt < 8; tt++) {
                    int lr = rg + 8 * tt;
                    int s = sbase + lr;
                    float v1 = EpS[lr * 261 + ch * 128 + d];
                    float v2 = EpS[lr * 261 + ch * 128 + 64 + d];
                    float2 cs = csT[(s << 6) + d];
                    float o1 = v1 * cs.x - v2 * cs.y;
                    float o2 = v2 * cs.x + v1 * cs.y;
                    if (t < 16) {
                        float w = hw[(size_t)((bb << 11) + s) * NHc + t] * SCALE;
                        size_t g = ((size_t)(bb * NHc + t) << 11) + s;
                        Qr[g * HDc + d]      = f2bf(o1 * w);
                        Qr[g * HDc + 64 + d] = f2bf(o2 * w);
                    } else {
                        size_t g = ((size_t)(bb * NKVc + (t - 16)) << 11) + s;
                        Kb[g * HDc + d]      = f2bf(o1);
                        Kb[g * HDc + 64 + d] = f2bf(o2);
                    }
                }
            }
        } else {
            // V transpose path + strided global-V gather, both heads
            const int sl = tid & 63, dg = tid >> 6;
            const int sg = sbase + sl;
#pragma unroll 1
            for (int ch = 0; ch < 2; ch++) {
                const int bhv = bb * NKVc + (tL + ch - 20);
                u16* Vbase = Vt + (size_t)bhv * HDc * Sc;
#pragma unroll
                for (int tt = 0; tt < 16; tt++) {
                    int d = dg + 8 * tt;
                    u16 bv = f2bf(EpS[sl * 261 + ch * 128 + d]);
                    Vbase[(size_t)d * Sc + sg] = bv;
                    if ((sg & 63) == 0)
                        Vg[(size_t)bhv * 4096 + d * 32 + (sg >> 6)] = bv;
                }
            }
        }
    }
}

// ---------------- bf16 GEMM (O-proj): 256x128 tile, 8-phase counted-vmcnt (R10) ----
// Verified R10 (283.8 us best). See R10 comments for vmcnt FIFO derivation.
__global__ __launch_bounds__(512, 2) void gemm_bt4(const u16* __restrict__ A,
                                                   const u16* __restrict__ Bw,
                                                   float* __restrict__ C,
                                                   int Mdim, int Ndim, int Kdim) {
    __shared__ __align__(16) u16 SA[2][2][128 * 64];   // 64 KB
    __shared__ __align__(16) u16 SB[2][128 * 64];      // 32 KB
    const int NT = Kdim >> 6;                          // 32
    const int tid  = threadIdx.x;
    const int lane = tid & 63;
    const int wid  = tid >> 6;
    const int m0 = blockIdx.y * 256;
    const int n0 = blockIdx.x * 128;
    const int wr = wid >> 2;            // 0..1 (M half, 128 rows)
    const int wc = wid & 3;             // 0..3 (N quarter, 32 cols)
    const int fr = lane & 15;
    const int fq = lane >> 4;
    const int f7 = fr & 7;

    // staging: thread's 2 slots per 128x64 half-tile
    const int s0 = tid, s1 = tid + 512;
    const int r0 = s0 >> 3, r1 = s1 >> 3;
    const int j0 = (s0 & 7) ^ (r0 & 7), j1 = (s1 & 7) ^ (r1 & 7);
    const u16* gA0 = A  + (size_t)(m0 + r0) * Kdim + j0 * 8;
    const u16* gA1 = A  + (size_t)(m0 + r1) * Kdim + j1 * 8;
    const u16* gB0 = Bw + (size_t)(n0 + r0) * Kdim + j0 * 8;
    const u16* gB1 = Bw + (size_t)(n0 + r1) * Kdim + j1 * 8;
    const size_t hK = (size_t)128 * Kdim;

    auto stA = [&](int buf, int h, int t) {
        async_cp16(gA0 + h * hK + t * 64, &SA[buf][h][s0 * 8]);
        async_cp16(gA1 + h * hK + t * 64, &SA[buf][h][s1 * 8]);
    };
    auto stB = [&](int buf, int t) {
        async_cp16(gB0 + t * 64, &SB[buf][s0 * 8]);
        async_cp16(gB1 + t * 64, &SB[buf][s1 * 8]);
    };

    f32x4 acc[8][2];
#pragma unroll
    for (int i = 0; i < 8; i++)
#pragma unroll
        for (int j = 0; j < 2; j++) {
            f32x4 z = {0.f, 0.f, 0.f, 0.f};
            acc[i][j] = z;
        }

    const int c0 = ((fq) ^ f7) * 8;       // ks=0 chunk offset (u16 units)
    const int c1 = ((4 + fq) ^ f7) * 8;   // ks=1 chunk
    bf16x8 afl[4][2], afh[4][2], bfl[2], bfh[2];

    auto rdA = [&](bf16x8 (&af)[4][2], int tb, int mh) {
        const u16* Ab = SA[tb][wr];       // wave wr reads only its row-half
#pragma unroll
        for (int m2 = 0; m2 < 4; m2++) {
            int row = (mh * 4 + m2) * 16 + fr;
            af[m2][0] = __builtin_bit_cast(bf16x8, *(const u16x8*)(Ab + row * 64 + c0));
            af[m2][1] = __builtin_bit_cast(bf16x8, *(const u16x8*)(Ab + row * 64 + c1));
        }
    };
    auto rdB = [&](bf16x8 (&bf)[2], int tb, int nh) {
        const u16* Bb = SB[tb];
        int row = wc * 32 + nh * 16 + fr;
        bf[0] = __builtin_bit_cast(bf16x8, *(const u16x8*)(Bb + row * 64 + c0));
        bf[1] = __builtin_bit_cast(bf16x8, *(const u16x8*)(Bb + row * 64 + c1));
    };
    auto mma = [&](bf16x8 (&af)[4][2], bf16x8 (&bf)[2], int mh, int nh) {
        __builtin_amdgcn_s_setprio(1);
#pragma unroll
        for (int m2 = 0; m2 < 4; m2++) {
            acc[mh * 4 + m2][nh] = __builtin_amdgcn_mfma_f32_16x16x32_bf16(
                af[m2][0], bf[0], acc[mh * 4 + m2][nh], 0, 0, 0);
            acc[mh * 4 + m2][nh] = __builtin_amdgcn_mfma_f32_16x16x32_bf16(
                af[m2][1], bf[1], acc[mh * 4 + m2][nh], 0, 0, 0);
        }
        __builtin_amdgcn_s_setprio(0);
    };

#define LGK0 do { asm volatile("s_waitcnt lgkmcnt(0)" ::: "memory"); \
                  __builtin_amdgcn_sched_barrier(0); } while (0)
#define BAR  __builtin_amdgcn_s_barrier()

    // prologue: tile0 (A0,A1,B) + tile1 B = 8 loads; vmcnt(2) -> tile0 landed, B(1) flies
    stA(0, 0, 0); stA(0, 1, 0); stB(0, 0);
    stB(1, 1);
    asm volatile("s_waitcnt vmcnt(2)" ::: "memory");
    BAR;

#pragma unroll 1
    for (int i = 0; i < NT / 2; i++) {
        const int t0 = 2 * i, t1 = 2 * i + 1;
        // ---- ph1: tile t0 quadrant (0,0) ----
        rdA(afl, 0, 0); rdB(bfl, 0, 0);
        stA(1, 0, t1);
        BAR; LGK0; mma(afl, bfl, 0, 0); BAR;
        // ---- ph2: (0,1) ----
        rdB(bfh, 0, 1);
        stA(1, 1, t1);
        BAR; LGK0; mma(afl, bfh, 0, 1); BAR;
        // ---- ph3: (1,0) ----
        rdA(afh, 0, 1);
        if (t0 + 2 < NT) stB(0, t0 + 2);
        BAR; LGK0; mma(afh, bfl, 1, 0); BAR;
        // ---- ph4: (1,1); counted vmcnt ----
        if (t0 + 2 < NT) {
            asm volatile("s_waitcnt vmcnt(2)" ::: "memory");
        } else {
            asm volatile("s_waitcnt vmcnt(0)" ::: "memory");   // tail
        }
        BAR; __builtin_amdgcn_sched_barrier(0); mma(afh, bfh, 1, 1); BAR;
        // ---- ph5: tile t1 quadrant (0,0) ----
        rdA(afl, 1, 0); rdB(bfl, 1, 0);
        if (t0 + 2 < NT) stA(0, 0, t0 + 2);
        BAR; LGK0; mma(afl, bfl, 0, 0); BAR;
        // ---- ph6: (0,1) ----
        rdB(bfh, 1, 1);
        if (t0 + 2 < NT) stA(0, 1, t0 + 2);
        BAR; LGK0; mma(afl, bfh, 0, 1); BAR;
        // ---- ph7: (1,0) ----
        rdA(afh, 1, 1);
        if (t1 + 2 < NT) stB(1, t1 + 2);
        BAR; LGK0; mma(afh, bfl, 1, 0); BAR;
        // ---- ph8: (1,1); counted vmcnt ----
        if (t1 + 2 < NT) {
            asm volatile("s_waitcnt vmcnt(2)" ::: "memory");
        } else {
            asm volatile("s_waitcnt vmcnt(0)" ::: "memory");   // tail: drains everything
        }
        BAR; __builtin_amdgcn_sched_barrier(0); mma(afh, bfh, 1, 1); BAR;
    }
#undef LGK0
#undef BAR

    // ---- epilogue: fp32 C write ----
#pragma unroll
    for (int i = 0; i < 8; i++)
#pragma unroll
        for (int j = 0; j < 2; j++) {
            int row = m0 + wr * 128 + i * 16 + fq * 4;
            int col = n0 + wc * 32 + j * 16 + fr;
#pragma unroll
            for (int r = 0; r < 4; r++)
                C[(size_t)(row + r) * Ndim + col] = acc[i][j][r];
        }
}

// ---------------- MFMA flash attention helpers ----------------
__device__ __forceinline__ float colreduce_max(f32x4 a, f32x4 b) {
    float m = fmaxf(fmaxf(fmaxf(a[0], a[1]), fmaxf(a[2], a[3])),
                    fmaxf(fmaxf(b[0], b[1]), fmaxf(b[2], b[3])));
    m = fmaxf(m, __shfl_xor(m, 16, 64));
    m = fmaxf(m, __shfl_xor(m, 32, 64));
    return m;
}

// exp(S^T) C-frags -> B-operand frag (K=32) for mfma_f32_16x16x32_bf16, via shuffles
__device__ __forceinline__ bf16x8 build_pfrag(u32 pk0, u32 pk1, u32 pk2, u32 pk3, int lane) {
    const int c = lane & 15, Q = lane >> 4;
    const int sl0 = ((Q & 1) * 2) * 16 + c;
    const int sl1 = sl0 + 16;
    u32 a0 = (u32)__shfl((int)pk0, sl0, 64), b0 = (u32)__shfl((int)pk2, sl0, 64);
    u32 a1 = (u32)__shfl((int)pk1, sl0, 64), b1 = (u32)__shfl((int)pk3, sl0, 64);
    u32 a2 = (u32)__shfl((int)pk0, sl1, 64), b2 = (u32)__shfl((int)pk2, sl1, 64);
    u32 a3 = (u32)__shfl((int)pk1, sl1, 64), b3 = (u32)__shfl((int)pk3, sl1, 64);
    const bool hi = Q >= 2;
    u32x4v r = { hi ? b0 : a0, hi ? b1 : a1, hi ? b2 : a2, hi ? b3 : a3 };
    return __builtin_bit_cast(bf16x8, r);
}

// ---------------- attn3: 256-thread blocks, 64 queries, LDS-staged K/V double buffer ----
// R11: + T5 (setprio around MFMA clusters; attn-proven m191 — independent unsynced
// blocks give the CU scheduler role diversity) and T13 (defer-max RESCALE_THRESHOLD=8,
// m239: skip the O-wide rescale when __all(mx <= mL+8); P bounded by e^8, f32-accum
// safe; first real stage always rescales since mL starts at -1e30; __all makes the
// branch wave-uniform).
__global__ __launch_bounds__(256) void attn3(const u16* __restrict__ Qr,
                                             const u16* __restrict__ Kb,
                                             const u16* __restrict__ Vt,
                                             const u16* __restrict__ Vg,
                                             u16* __restrict__ attnb) {
    __shared__ __align__(16) u16 Ksh[2 * 4096];
    __shared__ __align__(16) u16 Vsh[2 * 4096];
    const int tid  = threadIdx.x;
    const int lane = tid & 63, wid = tid >> 6;
    const int bid  = blockIdx.x;                   // 0..1023
    const int q64  = (31 - (bid >> 5)) << 6;       // heavy blocks dispatched first
    const int bh   = bid & 31;
    const int h    = bh & 15;
    const int b    = bh >> 4;
    const int qw   = q64 + wid * 16;
    const int c = lane & 15, Q = lane >> 4;
    const int kvh = h >> 2;

    const u16* Qp = Qr + ((size_t)((b * NHc + h) * Sc + qw)) * HDc;
    const u16* Kh = Kb + (size_t)(b * NKVc + kvh) * Sc * HDc;
    const u16* Vh = Vt + (size_t)(b * NKVc + kvh) * HDc * Sc;
    const u16* Vgh = Vg + (size_t)(b * NKVc + kvh) * HDc * 32;

    const int kp0 = (q64 >= 256) ? (q64 - 256) : 0;
    const int nstages = (q64 + 64 - kp0) >> 5;     // <= 10

    auto stageLoad = [&](int bufi, int kp) {
        u16* Kd = Ksh + bufi * 4096;
        u16* Vd = Vsh + bufi * 4096;
#pragma unroll
        for (int qq = 0; qq < 2; qq++) {
            int s = tid + qq * 256;
            int kr = s >> 4;
            int jk = (s & 15) ^ (kr & 15);
            async_cp16(Kh + (size_t)(kp + kr) * HDc + jk * 8, Kd + s * 8);
            int dv = s >> 2;
            int jv = (s & 3) ^ ((dv >> 2) & 3);
            async_cp16(Vh + (size_t)dv * Sc + kp + jv * 8, Vd + s * 8);
        }
    };

    bf16x8 qf[4];
#pragma unroll
    for (int ch = 0; ch < 4; ch++)
        qf[ch] = __builtin_bit_cast(bf16x8, *(const u16x8*)(Qp + c * HDc + ch * 32 + Q * 8));

    stageLoad(0, kp0);   // prologue

    // ---- global branch: 32 strided keys, unmasked, exact softmax ----
    f32x4 sg0 = {0.f,0.f,0.f,0.f}, sg1 = {0.f,0.f,0.f,0.f};
    __builtin_amdgcn_s_setprio(1);
#pragma unroll
    for (int ch = 0; ch < 4; ch++) {
        bf16x8 k0 = __builtin_bit_cast(bf16x8, *(const u16x8*)(Kh + ((size_t)c << 6) * HDc + ch * 32 + Q * 8));
        bf16x8 k1 = __builtin_bit_cast(bf16x8, *(const u16x8*)(Kh + ((size_t)(c + 16) << 6) * HDc + ch * 32 + Q * 8));
        sg0 = __builtin_amdgcn_mfma_f32_16x16x32_bf16(k0, qf[ch], sg0, 0, 0, 0);
        sg1 = __builtin_amdgcn_mfma_f32_16x16x32_bf16(k1, qf[ch], sg1, 0, 0, 0);
    }
    __builtin_amdgcn_s_setprio(0);
    float mg = colreduce_max(sg0, sg1);
    f32x4 pg0, pg1;
    float gsum = 0.f;
#pragma unroll
    for (int r = 0; r < 4; r++) {
        pg0[r] = __expf(sg0[r] - mg);
        pg1[r] = __expf(sg1[r] - mg);
        gsum += pg0[r] + pg1[r];
    }
    gsum += __shfl_xor(gsum, 16, 64);
    gsum += __shfl_xor(gsum, 32, 64);
    const float lG = gsum;
    bf16x8 pgf = build_pfrag(pk2bf(pg0[0], pg0[1]), pk2bf(pg0[2], pg0[3]),
                             pk2bf(pg1[0], pg1[1]), pk2bf(pg1[2], pg1[3]), lane);
    f32x4 OG[8];
    __builtin_amdgcn_s_setprio(1);
#pragma unroll
    for (int dt = 0; dt < 8; dt++) {
        bf16x8 vf = __builtin_bit_cast(bf16x8, *(const u16x8*)(Vgh + (dt * 16 + c) * 32 + Q * 8));
        f32x4 z = {0.f, 0.f, 0.f, 0.f};
        OG[dt] = __builtin_amdgcn_mfma_f32_16x16x32_bf16(vf, pgf, z, 0, 0, 0);
    }
    __builtin_amdgcn_s_setprio(0);

    // ---- local branch: window [q-256, q], online softmax over LDS-staged stages ----
    f32x4 OL[8];
#pragma unroll
    for (int dt = 0; dt < 8; dt++) { f32x4 z = {0.f,0.f,0.f,0.f}; OL[dt] = z; }
    float mL = -1e30f, lL = 0.f;

    for (int ip = 0; ip < nstages; ip++) {
        const int kp = kp0 + ip * 32;
        __syncthreads();
        if (ip + 1 < nstages) stageLoad((ip + 1) & 1, kp + 32);
        const u16* Kd = Ksh + (ip & 1) * 4096;
        const u16* Vd = Vsh + (ip & 1) * 4096;

        if (kp > qw + 15 || kp + 31 < qw - 256) continue;   // wave-uniform skip

        f32x4 s0 = {0.f,0.f,0.f,0.f}, s1 = {0.f,0.f,0.f,0.f};
        __builtin_amdgcn_s_setprio(1);
#pragma unroll
        for (int ch = 0; ch < 4; ch++) {
            int jj = ch * 4 + Q;
            bf16x8 k0 = __builtin_bit_cast(bf16x8, *(const u16x8*)(Kd + (c * 16 + (jj ^ c)) * 8));
            bf16x8 k1 = __builtin_bit_cast(bf16x8, *(const u16x8*)(Kd + ((16 + c) * 16 + (jj ^ c)) * 8));
            s0 = __builtin_amdgcn_mfma_f32_16x16x32_bf16(k0, qf[ch], s0, 0, 0, 0);
            s1 = __builtin_amdgcn_mfma_f32_16x16x32_bf16(k1, qf[ch], s1, 0, 0, 0);
        }
        __builtin_amdgcn_s_setprio(0);
        if ((kp + 31 > qw) || (kp < qw - 241)) {
            const int q = qw + c;
#pragma unroll
            for (int r = 0; r < 4; r++) {
                int kk0 = kp + Q * 4 + r;
                int kk1 = kk0 + 16;
                if (kk0 > q || kk0 + 256 < q) s0[r] = -1e30f;
                if (kk1 > q || kk1 + 256 < q) s1[r] = -1e30f;
            }
        }
        float mx = colreduce_max(s0, s1);
        // T13 defer-max: only rescale when some column's max grew past mL + 8.
        if (!__all(mx <= mL + 8.f)) {
            float mnew = fmaxf(mL, mx);
            float alpha = __expf(mL - mnew);
            lL *= alpha;
#pragma unroll
            for (int dt = 0; dt < 8; dt++) OL[dt] = OL[dt] * alpha;
            mL = mnew;
        }
        f32x4 p0, p1;
        float sum = 0.f;
#pragma unroll
        for (int r = 0; r < 4; r++) {
            p0[r] = __expf(s0[r] - mL);
            p1[r] = __expf(s1[r] - mL);
            sum += p0[r] + p1[r];
        }
        sum += __shfl_xor(sum, 16, 64);
        sum += __shfl_xor(sum, 32, 64);
        lL += sum;
        bf16x8 pf = build_pfrag(pk2bf(p0[0], p0[1]), pk2bf(p0[2], p0[3]),
                                pk2bf(p1[0], p1[1]), pk2bf(p1[2], p1[3]), lane);
        __builtin_amdgcn_s_setprio(1);
#pragma unroll
        for (int dt = 0; dt < 8; dt++) {
            int d = dt * 16 + c;
            bf16x8 vf = __builtin_bit_cast(bf16x8, *(const u16x8*)(Vd + (d * 4 + (Q ^ (c >> 2))) * 8));
            OL[dt] = __builtin_amdgcn_mfma_f32_16x16x32_bf16(vf, pf, OL[dt], 0, 0, 0);
        }
        __builtin_amdgcn_s_setprio(0);
    }

    // ---- epilogue: 0.7*local + 0.3*global, write bf16 [B,S,DIM] ----
    const float rL = 0.7f / lL, rG = 0.3f / lG;
    u16* orow = attnb + ((size_t)(b * Sc + qw + c)) * DIMc + h * HDc;
#pragma unroll
    for (int dt = 0; dt < 8; dt++) {
        ushort4 ov;
        ov.x = f2bf(OL[dt][0] * rL + OG[dt][0] * rG);
        ov.y = f2bf(OL[dt][1] * rL + OG[dt][1] * rG);
        ov.z = f2bf(OL[dt][2] * rL + OG[dt][2] * rG);
        ov.w = f2bf(OL[dt][3] * rL + OG[dt][3] * rG);
        *(ushort4*)(orow + dt * 16 + Q * 4) = ov;
    }
}

extern "C" void kernel_launch(void* const* d_in, const int* in_sizes, int n_in,
                              void* d_out, int out_size, void* d_ws, size_t ws_size,
                              hipStream_t stream) {
    const float* x   = (const float*)d_in[0];
    const float* Wq  = (const float*)d_in[1];
    const float* Wkv = (const float*)d_in[2];
    const float* Wo  = (const float*)d_in[3];
    const float* Wr  = (const float*)d_in[4];
    const float* br  = (const float*)d_in[5];
    float* out = (float*)d_out;

    // workspace layout (~98 MB)
    char* p = (char*)d_ws;
    u16* xb    = (u16*)p;   p += (size_t)Mc * DIMc * 2;
    u16* Wqkvb = (u16*)p;   p += (size_t)QKVN * DIMc * 2;    // Wq rows then Wkv rows
    u16* Wob   = (u16*)p;   p += (size_t)DIMc * DIMc * 2;
    float* hw  = (float*)p; p += (size_t)Mc * NHc * 4;
    float2* csT = (float2*)p; p += (size_t)Sc * 64 * 8;      // rope cos/sin table, 1 MB
    u16* Qrb   = (u16*)p;   p += (size_t)Mc * DIMc * 2;
    u16* Kb16  = (u16*)p;   p += (size_t)Bc * NKVc * Sc * HDc * 2;
    u16* Vt16  = (u16*)p;   p += (size_t)Bc * NKVc * HDc * Sc * 2;
    u16* Vg16  = (u16*)p;   p += (size_t)Bc * NKVc * HDc * 32 * 2;
    u16* attnb = (u16*)p;   p += (size_t)Mc * DIMc * 2;

    cvt_hw<<<HWB + NWQ + NTB, 256, 0, stream>>>(x, Wq, Wkv, Wr, br, xb, Wqkvb, hw, csT);

    // 1D grid: 192 GEMM tiles + 64 Wo-cast blocks = 256 = full chip
    gemm_qkv<<<256, 512, 0, stream>>>(xb, Wqkvb, hw, csT, Wo, Wob, Qrb, Kb16, Vt16, Vg16);

    attn3<<<Bc * NHc * (Sc / 64), 256, 0, stream>>>(Qrb, Kb16, Vt16, Vg16, attnb);

    dim3 go(DIMc / 128, Mc / 256);     // (16, 16) = 256 blocks, 512 threads, 1 block/CU
    gemm_bt4<<<go, 512, 0, stream>>>(attnb, Wob, out, Mc, DIMc, DIMc);
}